// Round 1
// baseline (474.837 us; speedup 1.0000x reference)
//
#include <hip/hip_runtime.h>
#include <hip/hip_bf16.h>
#include <math.h>

// Problem constants: B=4, N=8, T=512, D=256, H=8, DK=32.
// BN = 32 sequences, ROWS = BN*T = 16384.

// Workspace layout (float offsets). Total = 17,170,944 floats = 65.5 MiB.
#define WS_MQ   0          // 3*256*256 folded Q matrices
#define WS_MK   196608
#define WS_BQ   393216     // effective biases (256 each)
#define WS_BK   393472
#define WS_Q    393728     // projected Q (16384 x 256)
#define WS_K    4588032
#define WS_V    8782336
#define WS_CTX  12976640

// ---------------- fold conv weights into 3 effective DxD matrices ----------------
// M[j][c][n] = w_pos[c,j]*W[c,n] + w_vel[c,j]*W[256+c,n] + w_acc[c,j]*W[512+c,n]
__global__ __launch_bounds__(256) void eff_mats_kernel(
    const float* __restrict__ Wq, const float* __restrict__ Wk,
    const float* __restrict__ w_pos, const float* __restrict__ w_vel,
    const float* __restrict__ w_acc, float* __restrict__ ws)
{
    int idx = blockIdx.x * 256 + threadIdx.x;   // 0 .. 393215 (2 * 3 * 256 * 256)
    int which = idx / 196608;
    int r = idx - which * 196608;
    int j = r >> 16;            // tap 0..2
    int rem = r & 65535;
    int d = rem >> 8;           // channel
    int n = rem & 255;          // output feature
    const float* W = which ? Wk : Wq;
    float wp = w_pos[d * 3 + j];
    float wv = w_vel[d * 3 + j];
    float wa = w_acc[d * 3 + j];
    float val = wp * W[d * 256 + n] + wv * W[(256 + d) * 256 + n] + wa * W[(512 + d) * 256 + n];
    ws[which * 196608 + j * 65536 + d * 256 + n] = val;
}

// b_eff[n] = b[n] + sum_d b_pos[d] * W[d,n]   (p-rows of W only)
__global__ __launch_bounds__(256) void eff_bias_kernel(
    const float* __restrict__ Wq, const float* __restrict__ Wk,
    const float* __restrict__ bq, const float* __restrict__ bk,
    const float* __restrict__ b_pos, float* __restrict__ ws)
{
    int which = blockIdx.x;     // 0 = q, 1 = k
    int n = threadIdx.x;
    const float* W = which ? Wk : Wq;
    const float* bb = which ? bk : bq;
    float s = bb[n];
    for (int d = 0; d < 256; ++d) s = fmaf(b_pos[d], W[d * 256 + n], s);
    ws[WS_BQ + which * 256 + n] = s;
}

// ---------------- Q/K projection: im2col GEMM, K-dim = 768 (3 taps x 256 ch) ----------------
// Out[t,:] = x(t-1) @ M0 + x(t) @ M1 + x(t+1) @ M2 + beff   (zero-padded at seq edges)
__global__ __launch_bounds__(256) void qkproj_kernel(
    const float* __restrict__ X, const float* __restrict__ M3,
    const float* __restrict__ beff, float* __restrict__ Out)
{
    __shared__ float As[64][36];   // [row][kk], +pad for aligned float4 reads
    __shared__ float Bs[32][64];   // [kk][n]
    const int m0 = blockIdx.x * 64;
    const int n0 = blockIdx.y * 64;
    const int seq = m0 >> 9;       // 512 rows per sequence; 64 | 512 so tile is in one seq
    const int t0 = m0 & 511;
    const int tid = threadIdx.x;
    const int tx = tid & 15, ty = tid >> 4;

    float acc[4][4] = {};
    for (int k0 = 0; k0 < 768; k0 += 32) {
        const int j = k0 >> 8;         // tap
        const int c0 = k0 & 255;       // channel offset
        #pragma unroll
        for (int i = 0; i < 8; ++i) {
            int idx = i * 256 + tid;
            int m = idx >> 5;
            int kk = tid & 31;
            int st = t0 + m + j - 1;
            float v = 0.f;
            if (st >= 0 && st < 512) v = X[(seq * 512 + st) * 256 + c0 + kk];
            As[m][kk] = v;
        }
        #pragma unroll
        for (int i = 0; i < 8; ++i) {
            int idx = i * 256 + tid;
            int kk = idx >> 6;
            int n = idx & 63;
            Bs[kk][n] = M3[(k0 + kk) * 256 + n0 + n];
        }
        __syncthreads();
        #pragma unroll
        for (int kk = 0; kk < 32; kk += 4) {
            float a[4][4], b[4][4];
            #pragma unroll
            for (int r = 0; r < 4; ++r) {
                float4 av = *(const float4*)&As[ty * 4 + r][kk];
                a[r][0] = av.x; a[r][1] = av.y; a[r][2] = av.z; a[r][3] = av.w;
            }
            #pragma unroll
            for (int jj = 0; jj < 4; ++jj) {
                float4 bv = *(const float4*)&Bs[kk + jj][tx * 4];
                b[jj][0] = bv.x; b[jj][1] = bv.y; b[jj][2] = bv.z; b[jj][3] = bv.w;
            }
            #pragma unroll
            for (int jj = 0; jj < 4; ++jj)
                #pragma unroll
                for (int r = 0; r < 4; ++r)
                    #pragma unroll
                    for (int c = 0; c < 4; ++c)
                        acc[r][c] = fmaf(a[r][jj], b[jj][c], acc[r][c]);
        }
        __syncthreads();
    }
    float4 bv4 = *(const float4*)&beff[n0 + tx * 4];
    float bb[4] = {bv4.x, bv4.y, bv4.z, bv4.w};
    #pragma unroll
    for (int r = 0; r < 4; ++r) {
        float4 o;
        o.x = acc[r][0] + bb[0];
        o.y = acc[r][1] + bb[1];
        o.z = acc[r][2] + bb[2];
        o.w = acc[r][3] + bb[3];
        *(float4*)&Out[(m0 + ty * 4 + r) * 256 + n0 + tx * 4] = o;
    }
}

// ---------------- plain GEMM (16384 x 256) @ (256 x 256) + bias ----------------
__global__ __launch_bounds__(256) void gemm256_kernel(
    const float* __restrict__ A, const float* __restrict__ Bm,
    const float* __restrict__ bias, float* __restrict__ Out)
{
    __shared__ float As[64][36];
    __shared__ float Bs[32][64];
    const int m0 = blockIdx.x * 64;
    const int n0 = blockIdx.y * 64;
    const int tid = threadIdx.x;
    const int tx = tid & 15, ty = tid >> 4;

    float acc[4][4] = {};
    for (int k0 = 0; k0 < 256; k0 += 32) {
        #pragma unroll
        for (int i = 0; i < 8; ++i) {
            int idx = i * 256 + tid;
            int m = idx >> 5;
            int kk = tid & 31;
            As[m][kk] = A[(m0 + m) * 256 + k0 + kk];
        }
        #pragma unroll
        for (int i = 0; i < 8; ++i) {
            int idx = i * 256 + tid;
            int kk = idx >> 6;
            int n = idx & 63;
            Bs[kk][n] = Bm[(k0 + kk) * 256 + n0 + n];
        }
        __syncthreads();
        #pragma unroll
        for (int kk = 0; kk < 32; kk += 4) {
            float a[4][4], b[4][4];
            #pragma unroll
            for (int r = 0; r < 4; ++r) {
                float4 av = *(const float4*)&As[ty * 4 + r][kk];
                a[r][0] = av.x; a[r][1] = av.y; a[r][2] = av.z; a[r][3] = av.w;
            }
            #pragma unroll
            for (int jj = 0; jj < 4; ++jj) {
                float4 bv = *(const float4*)&Bs[kk + jj][tx * 4];
                b[jj][0] = bv.x; b[jj][1] = bv.y; b[jj][2] = bv.z; b[jj][3] = bv.w;
            }
            #pragma unroll
            for (int jj = 0; jj < 4; ++jj)
                #pragma unroll
                for (int r = 0; r < 4; ++r)
                    #pragma unroll
                    for (int c = 0; c < 4; ++c)
                        acc[r][c] = fmaf(a[r][jj], b[jj][c], acc[r][c]);
        }
        __syncthreads();
    }
    float4 bv4 = *(const float4*)&bias[n0 + tx * 4];
    float bb[4] = {bv4.x, bv4.y, bv4.z, bv4.w};
    #pragma unroll
    for (int r = 0; r < 4; ++r) {
        float4 o;
        o.x = acc[r][0] + bb[0];
        o.y = acc[r][1] + bb[1];
        o.z = acc[r][2] + bb[2];
        o.w = acc[r][3] + bb[3];
        *(float4*)&Out[(m0 + ty * 4 + r) * 256 + n0 + tx * 4] = o;
    }
}

// ---------------- fused attention: per (b,n,h), 64-q-row tiles, online softmax ----------------
// grid = (8 q-tiles, 256 bnh). Each block: Q tile in LDS, stream K/V in 64-row tiles.
__global__ __launch_bounds__(256) void attn_kernel(
    const float* __restrict__ Q, const float* __restrict__ K,
    const float* __restrict__ V, const int* __restrict__ mask,
    float* __restrict__ CTX)
{
    __shared__ float Qs[64][36];    // [qrow][d]
    __shared__ float KsT[32][68];   // [d][kcol]  (transposed for GEMM-style reads)
    __shared__ float Vs[64][36];    // [krow][d]
    __shared__ float Ps[64][68];    // [qrow][kcol] probabilities
    __shared__ float Msk[64];

    const int qt = blockIdx.x;          // 0..7
    const int bnh = blockIdx.y;         // 0..255
    const int bn = bnh >> 3, h = bnh & 7;
    const int t0 = qt * 64;
    const int tid = threadIdx.x;
    const int tx = tid & 15, ty = tid >> 4;

    const float* Qg = Q + (size_t)bn * 512 * 256 + h * 32;
    const float* Kg = K + (size_t)bn * 512 * 256 + h * 32;
    const float* Vg = V + (size_t)bn * 512 * 256 + h * 32;
    const int* mp = mask + bn * 512;

    #pragma unroll
    for (int i = 0; i < 8; ++i) {
        int idx = i * 256 + tid;
        int m = idx >> 5;
        int d = tid & 31;
        Qs[m][d] = Qg[(t0 + m) * 256 + d];
    }

    float m_run[4], l_run[4], acc[4][2];
    #pragma unroll
    for (int r = 0; r < 4; ++r) { m_run[r] = -1e30f; l_run[r] = 0.f; acc[r][0] = 0.f; acc[r][1] = 0.f; }

    const float scale = 0.17677669529663689f;   // 1/sqrt(32)

    for (int kt = 0; kt < 8; ++kt) {
        const int k0 = kt * 64;
        __syncthreads();   // previous PV done (Vs/Ps free); also covers Qs on first iter
        #pragma unroll
        for (int i = 0; i < 8; ++i) {
            int idx = i * 256 + tid;
            int kc = idx >> 5;
            int d = tid & 31;
            float kv = Kg[(k0 + kc) * 256 + d];
            KsT[d][kc] = kv;
            Vs[kc][d] = Vg[(k0 + kc) * 256 + d];
        }
        if (tid < 64) Msk[tid] = (mp[k0 + tid] != 0) ? 1.f : 0.f;
        __syncthreads();

        // scores tile: s[r][c] = Q[t0+ty*4+r] . K[k0+tx*4+c]
        float s[4][4] = {};
        #pragma unroll
        for (int d0 = 0; d0 < 32; d0 += 4) {
            float a[4][4], b[4][4];
            #pragma unroll
            for (int r = 0; r < 4; ++r) {
                float4 av = *(const float4*)&Qs[ty * 4 + r][d0];
                a[r][0] = av.x; a[r][1] = av.y; a[r][2] = av.z; a[r][3] = av.w;
            }
            #pragma unroll
            for (int jj = 0; jj < 4; ++jj) {
                float4 bv = *(const float4*)&KsT[d0 + jj][tx * 4];
                b[jj][0] = bv.x; b[jj][1] = bv.y; b[jj][2] = bv.z; b[jj][3] = bv.w;
            }
            #pragma unroll
            for (int jj = 0; jj < 4; ++jj)
                #pragma unroll
                for (int r = 0; r < 4; ++r)
                    #pragma unroll
                    for (int c = 0; c < 4; ++c)
                        s[r][c] = fmaf(a[r][jj], b[jj][c], s[r][c]);
        }

        // scale + mask (mask==1 -> -1e9, matching reference)
        float msk4[4];
        #pragma unroll
        for (int c = 0; c < 4; ++c) msk4[c] = Msk[tx * 4 + c];
        #pragma unroll
        for (int r = 0; r < 4; ++r)
            #pragma unroll
            for (int c = 0; c < 4; ++c) {
                float v = s[r][c] * scale;
                s[r][c] = (msk4[c] != 0.f) ? -1e9f : v;
            }

        // tile row max across the 16 lanes sharing this row group
        float rm[4];
        #pragma unroll
        for (int r = 0; r < 4; ++r)
            rm[r] = fmaxf(fmaxf(s[r][0], s[r][1]), fmaxf(s[r][2], s[r][3]));
        #pragma unroll
        for (int off = 1; off < 16; off <<= 1)
            #pragma unroll
            for (int r = 0; r < 4; ++r)
                rm[r] = fmaxf(rm[r], __shfl_xor(rm[r], off));

        // online softmax update
        float ps[4];
        #pragma unroll
        for (int r = 0; r < 4; ++r) {
            float mn = fmaxf(m_run[r], rm[r]);
            float sf = __expf(m_run[r] - mn);
            l_run[r] *= sf;
            acc[r][0] *= sf;
            acc[r][1] *= sf;
            m_run[r] = mn;
            float psum = 0.f;
            #pragma unroll
            for (int c = 0; c < 4; ++c) {
                float p = __expf(s[r][c] - mn);
                s[r][c] = p;
                psum += p;
            }
            ps[r] = psum;
        }
        #pragma unroll
        for (int off = 1; off < 16; off <<= 1)
            #pragma unroll
            for (int r = 0; r < 4; ++r)
                ps[r] += __shfl_xor(ps[r], off);
        #pragma unroll
        for (int r = 0; r < 4; ++r) l_run[r] += ps[r];

        // P tile to LDS for the PV GEMM
        #pragma unroll
        for (int r = 0; r < 4; ++r) {
            float4 o; o.x = s[r][0]; o.y = s[r][1]; o.z = s[r][2]; o.w = s[r][3];
            *(float4*)&Ps[ty * 4 + r][tx * 4] = o;
        }
        __syncthreads();

        // ctx accumulate: acc[r][0..1] += P[row] . V[:, tx*2 + 0..1]
        #pragma unroll
        for (int kc = 0; kc < 64; kc += 4) {
            float pa[4][4];
            #pragma unroll
            for (int r = 0; r < 4; ++r) {
                float4 pv = *(const float4*)&Ps[ty * 4 + r][kc];
                pa[r][0] = pv.x; pa[r][1] = pv.y; pa[r][2] = pv.z; pa[r][3] = pv.w;
            }
            #pragma unroll
            for (int j2 = 0; j2 < 4; ++j2) {
                float2 vb = *(const float2*)&Vs[kc + j2][tx * 2];
                #pragma unroll
                for (int r = 0; r < 4; ++r) {
                    acc[r][0] = fmaf(pa[r][j2], vb.x, acc[r][0]);
                    acc[r][1] = fmaf(pa[r][j2], vb.y, acc[r][1]);
                }
            }
        }
    }

    #pragma unroll
    for (int r = 0; r < 4; ++r) {
        float inv = 1.f / l_run[r];
        float2 o;
        o.x = acc[r][0] * inv;
        o.y = acc[r][1] * inv;
        *(float2*)&CTX[((size_t)bn * 512 + t0 + ty * 4 + r) * 256 + h * 32 + tx * 2] = o;
    }
}

extern "C" void kernel_launch(void* const* d_in, const int* in_sizes, int n_in,
                              void* d_out, int out_size, void* d_ws, size_t ws_size,
                              hipStream_t stream) {
    const float* query = (const float*)d_in[0];
    const float* key   = (const float*)d_in[1];
    const float* value = (const float*)d_in[2];
    const int*   kpm   = (const int*)d_in[3];
    const float* w_pos = (const float*)d_in[4];
    const float* b_pos = (const float*)d_in[5];
    const float* w_vel = (const float*)d_in[6];
    const float* w_acc = (const float*)d_in[7];
    const float* Wq    = (const float*)d_in[8];
    const float* bq    = (const float*)d_in[9];
    const float* Wk    = (const float*)d_in[10];
    const float* bk    = (const float*)d_in[11];
    const float* Wv    = (const float*)d_in[12];
    const float* bv    = (const float*)d_in[13];
    const float* Wo    = (const float*)d_in[14];
    const float* bo    = (const float*)d_in[15];
    float* out = (float*)d_out;
    float* ws  = (float*)d_ws;

    // fold depthwise-conv + projection into 3 effective DxD matrices (+bias) each for Q,K
    eff_mats_kernel<<<1536, 256, 0, stream>>>(Wq, Wk, w_pos, w_vel, w_acc, ws);
    eff_bias_kernel<<<2, 256, 0, stream>>>(Wq, Wk, bq, bk, b_pos, ws);

    // projections
    qkproj_kernel<<<dim3(256, 4), 256, 0, stream>>>(query, ws + WS_MQ, ws + WS_BQ, ws + WS_Q);
    qkproj_kernel<<<dim3(256, 4), 256, 0, stream>>>(key,   ws + WS_MK, ws + WS_BK, ws + WS_K);
    gemm256_kernel<<<dim3(256, 4), 256, 0, stream>>>(value, Wv, bv, ws + WS_V);

    // fused attention -> ctx
    attn_kernel<<<dim3(8, 256), 256, 0, stream>>>(ws + WS_Q, ws + WS_K, ws + WS_V, kpm, ws + WS_CTX);

    // output projection
    gemm256_kernel<<<dim3(256, 4), 256, 0, stream>>>(ws + WS_CTX, Wo, bo, out);
}

// Round 2
// 116.924 us; speedup vs baseline: 4.0611x; 4.0611x over previous
//
#include <hip/hip_runtime.h>
#include <math.h>

// B=4, N=8, T=512, D=256, H=8, DK=32. BN=32, ROWS=16384.
// Full-bf16 MFMA pipeline. fp32 accumulate everywhere; Wo split hi/lo.

typedef __attribute__((ext_vector_type(8))) short bf16x8;
typedef __attribute__((ext_vector_type(4))) float f32x4;
typedef __attribute__((ext_vector_type(4))) int i32x4;

__device__ __forceinline__ unsigned short f2bf(float f) {
    unsigned u = __float_as_uint(f);
    return (unsigned short)((u + 0x7fff + ((u >> 16) & 1)) >> 16);
}
__device__ __forceinline__ float bf2f(unsigned short h) {
    return __uint_as_float(((unsigned)h) << 16);
}
__device__ __forceinline__ void gll16(const void* gsrc, const void* ldst) {
    __builtin_amdgcn_global_load_lds(
        (const __attribute__((address_space(1))) unsigned int*)gsrc,
        (__attribute__((address_space(3))) unsigned int*)ldst, 16, 0, 0);
}

// ---- workspace byte offsets ----
#define OFF_XPQ  0u           // 32*514*256 bf16 = 8,421,376
#define OFF_XPK  8421376u
#define OFF_VB   16842752u    // 16384*256 bf16
#define OFF_BTQ  25231360u    // 256*768 bf16
#define OFF_BTK  25624576u
#define OFF_BEFF 26017792u    // 2*256 f32
#define OFF_WVT  26019840u    // 256*256 bf16
#define OFF_WOT  26150912u    // 256*512 bf16 (hi|lo)
#define OFF_QB   26413056u    // 16384*256 bf16
#define OFF_KB   34801664u
#define OFF_VV   43190272u
#define OFF_CTX  51578880u

// ---------------- input conversion: pad Q,K to [32][514][256] bf16 ----------------
__global__ __launch_bounds__(256) void cvt_pad(const float* __restrict__ q,
                                               const float* __restrict__ k,
                                               unsigned short* __restrict__ xpq,
                                               unsigned short* __restrict__ xpk) {
    int idx = blockIdx.x * 256 + threadIdx.x;        // 2 * 32 * 514 * 32
    int which = idx / 526336;
    int r = idx - which * 526336;
    int bn = r / 16448;
    int rr = r - bn * 16448;
    int p = rr >> 5;
    int c8 = (rr & 31) * 8;
    const float* src = which ? k : q;
    unsigned short* dst = which ? xpk : xpq;
    unsigned o[4] = {0, 0, 0, 0};
    if (p != 0 && p != 513) {
        const float* s = src + ((size_t)(bn * 512 + p - 1) * 256 + c8);
        float4 a = *(const float4*)s;
        float4 b = *(const float4*)(s + 4);
        o[0] = f2bf(a.x) | ((unsigned)f2bf(a.y) << 16);
        o[1] = f2bf(a.z) | ((unsigned)f2bf(a.w) << 16);
        o[2] = f2bf(b.x) | ((unsigned)f2bf(b.y) << 16);
        o[3] = f2bf(b.z) | ((unsigned)f2bf(b.w) << 16);
    }
    unsigned* d = (unsigned*)(dst + ((size_t)(bn * 514 + p) * 256 + c8));
    d[0] = o[0]; d[1] = o[1]; d[2] = o[2]; d[3] = o[3];
}

__global__ __launch_bounds__(256) void cvt_v(const float* __restrict__ v,
                                             unsigned short* __restrict__ vb) {
    int idx = blockIdx.x * 256 + threadIdx.x;   // 16384*32
    int row = idx >> 5;
    int c8 = (idx & 31) * 8;
    const float* s = v + ((size_t)row * 256 + c8);
    float4 a = *(const float4*)s;
    float4 b = *(const float4*)(s + 4);
    unsigned o0 = f2bf(a.x) | ((unsigned)f2bf(a.y) << 16);
    unsigned o1 = f2bf(a.z) | ((unsigned)f2bf(a.w) << 16);
    unsigned o2 = f2bf(b.x) | ((unsigned)f2bf(b.y) << 16);
    unsigned o3 = f2bf(b.z) | ((unsigned)f2bf(b.w) << 16);
    unsigned* d = (unsigned*)(vb + ((size_t)row * 256 + c8));
    d[0] = o0; d[1] = o1; d[2] = o2; d[3] = o3;
}

// ---------------- fold conv weights -> transposed bf16 B matrices [256 n][768 k] ----------------
__global__ __launch_bounds__(256) void eff_mats(const float* __restrict__ Wq,
                                                const float* __restrict__ Wk,
                                                const float* __restrict__ wp,
                                                const float* __restrict__ wv,
                                                const float* __restrict__ wa,
                                                unsigned short* __restrict__ BtQ,
                                                unsigned short* __restrict__ BtK) {
    int idx = blockIdx.x * 256 + threadIdx.x;   // 2*3*256*256
    int which = idx / 196608;
    int r = idx - which * 196608;
    int j = r >> 16;
    int rem = r & 65535;
    int n = rem >> 8;
    int d = rem & 255;
    const float* W = which ? Wk : Wq;
    float val = wp[d * 3 + j] * W[d * 256 + n]
              + wv[d * 3 + j] * W[(256 + d) * 256 + n]
              + wa[d * 3 + j] * W[(512 + d) * 256 + n];
    (which ? BtK : BtQ)[n * 768 + j * 256 + d] = f2bf(val);
}

__global__ __launch_bounds__(256) void eff_bias(const float* __restrict__ Wq,
                                                const float* __restrict__ Wk,
                                                const float* __restrict__ bq,
                                                const float* __restrict__ bk,
                                                const float* __restrict__ b_pos,
                                                float* __restrict__ beff) {
    int which = blockIdx.x;
    int n = threadIdx.x;
    const float* W = which ? Wk : Wq;
    const float* bb = which ? bk : bq;
    float s = bb[n];
    for (int d = 0; d < 256; ++d) s = fmaf(b_pos[d], W[d * 256 + n], s);
    beff[which * 256 + n] = s;
}

// ---------------- transpose Wv -> [n][k] bf16; Wo -> [n][512] hi|lo bf16 ----------------
__global__ __launch_bounds__(256) void wconv(const float* __restrict__ Wv,
                                             const float* __restrict__ Wo,
                                             unsigned short* __restrict__ WVT,
                                             unsigned short* __restrict__ WOT) {
    int idx = blockIdx.x * 256 + threadIdx.x;   // 2*65536
    int which = idx >> 16;
    int r = idx & 65535;
    int n = r >> 8, k = r & 255;
    if (!which) {
        WVT[n * 256 + k] = f2bf(Wv[k * 256 + n]);
    } else {
        float v = Wo[k * 256 + n];
        unsigned short hi = f2bf(v);
        WOT[n * 512 + k] = hi;
        WOT[n * 512 + 256 + k] = f2bf(v - bf2f(hi));
    }
}

// ---------------- MFMA GEMM: [16384 x KTOT] x [KTOT x 256] + bias ----------------
// IM2COL: A is padded X [32][514][256], k = tap*256 + channel.
// AMASK: A column index = k & AMASK (for hi/lo-split B with K=512 over a 256-wide A).
template<int KTOT, bool IM2COL, int AMASK, typename OutT>
__global__ __launch_bounds__(256) void gemm_mfma(const unsigned short* __restrict__ A,
                                                 const unsigned short* __restrict__ Bt,
                                                 const float* __restrict__ bias,
                                                 OutT* __restrict__ Out) {
    __shared__ alignas(16) unsigned short As[64 * 32];
    __shared__ alignas(16) unsigned short Bs[64 * 32];
    const int tid = threadIdx.x;
    const int wid = tid >> 6, l = tid & 63;
    const int g = l >> 4, r15 = l & 15;
    const int wm = wid >> 1, wn = wid & 1;
    const int m0 = blockIdx.x * 64, n0 = blockIdx.y * 64;
    const int drow = tid >> 2;          // staging dest row 0..63
    const int dc8 = (tid & 3) * 8;      // staging dest col (bf16)
    const unsigned short* ldsA = As + wid * 512;
    const unsigned short* ldsB = Bs + wid * 512;

    f32x4 acc[2][2] = {};
    for (int k0 = 0; k0 < KTOT; k0 += 32) {
        __syncthreads();
        const unsigned short* asrc;
        if (IM2COL) {
            const int seq = m0 >> 9, t0 = m0 & 511;
            const int j = k0 >> 8, c0 = k0 & 255;
            asrc = A + ((size_t)(seq * 514 + t0 + drow + j) * 256 + c0 + dc8);
        } else {
            asrc = A + ((size_t)(m0 + drow) * (AMASK + 1) + ((k0 & AMASK) + dc8));
        }
        gll16(asrc, ldsA);
        gll16(Bt + ((size_t)(n0 + drow) * KTOT + k0 + dc8), ldsB);
        __syncthreads();

        bf16x8 af0 = *(const bf16x8*)&As[(wm * 32 + r15) * 32 + g * 8];
        bf16x8 af1 = *(const bf16x8*)&As[(wm * 32 + 16 + r15) * 32 + g * 8];
        bf16x8 bf0 = *(const bf16x8*)&Bs[(wn * 32 + r15) * 32 + g * 8];
        bf16x8 bf1 = *(const bf16x8*)&Bs[(wn * 32 + 16 + r15) * 32 + g * 8];
        acc[0][0] = __builtin_amdgcn_mfma_f32_16x16x32_bf16(af0, bf0, acc[0][0], 0, 0, 0);
        acc[0][1] = __builtin_amdgcn_mfma_f32_16x16x32_bf16(af0, bf1, acc[0][1], 0, 0, 0);
        acc[1][0] = __builtin_amdgcn_mfma_f32_16x16x32_bf16(af1, bf0, acc[1][0], 0, 0, 0);
        acc[1][1] = __builtin_amdgcn_mfma_f32_16x16x32_bf16(af1, bf1, acc[1][1], 0, 0, 0);
    }

    #pragma unroll
    for (int nt = 0; nt < 2; ++nt) {
        const int col = n0 + wn * 32 + nt * 16 + r15;
        const float bb = bias[col];
        #pragma unroll
        for (int mt = 0; mt < 2; ++mt) {
            #pragma unroll
            for (int r = 0; r < 4; ++r) {
                const size_t row = m0 + wm * 32 + mt * 16 + 4 * g + r;
                float v = acc[mt][nt][r] + bb;
                if constexpr (sizeof(OutT) == 2) Out[row * 256 + col] = (OutT)f2bf(v);
                else Out[row * 256 + col] = (OutT)v;
            }
        }
    }
}

// ---------------- fused MFMA flash attention ----------------
// Swapped QK^T (S^T = K_tile x Q^T) with permuted A rows so each lane's P values
// are exactly its PV B-fragment keys: zero cross-lane exchange for P.
__global__ __launch_bounds__(256) void attn_mfma(const unsigned short* __restrict__ Qb,
                                                 const unsigned short* __restrict__ Kb,
                                                 const unsigned short* __restrict__ Vv,
                                                 const int* __restrict__ mask,
                                                 unsigned short* __restrict__ ctx) {
    __shared__ alignas(16) unsigned short Qs[64 * 32];
    __shared__ alignas(16) unsigned short Ks[64 * 32];
    __shared__ alignas(16) unsigned short VsT[32 * 72];   // [d][key], padded rows
    __shared__ float Msk[64];

    const int qt = blockIdx.x, bnh = blockIdx.y;
    const int bn = bnh >> 3, h = bnh & 7;
    const int tid = threadIdx.x, wid = tid >> 6, l = tid & 63;
    const int g = l >> 4, r15 = l & 15;
    const unsigned short* Qg = Qb + (size_t)bn * 512 * 256 + h * 32;
    const unsigned short* Kg = Kb + (size_t)bn * 512 * 256 + h * 32;
    const unsigned short* Vg = Vv + (size_t)bn * 512 * 256 + h * 32;
    const int* mp = mask + bn * 512;
    const int drow = tid >> 2, dc8 = (tid & 3) * 8;

    gll16(Qg + ((size_t)(qt * 64 + drow)) * 256 + dc8, Qs + wid * 512);

    float mrun = -1e30f, lrun = 0.f;
    f32x4 accO[2] = {};
    const float scale = 0.17677669529663689f;   // 1/sqrt(32)

    for (int kt = 0; kt < 8; ++kt) {
        const int k0 = kt * 64;
        __syncthreads();   // prev-iter reads done (first iter: drains Q stage)
        gll16(Kg + ((size_t)(k0 + drow)) * 256 + dc8, Ks + wid * 512);
        {
            const int key = tid & 63, d0 = (tid >> 6) * 8;
            i32x4 vvld = *(const i32x4*)(const void*)(Vg + ((size_t)(k0 + key)) * 256 + d0);
            #pragma unroll
            for (int i = 0; i < 4; ++i) {
                unsigned u = (unsigned)vvld[i];
                VsT[(d0 + 2 * i) * 72 + key] = (unsigned short)(u & 0xffff);
                VsT[(d0 + 2 * i + 1) * 72 + key] = (unsigned short)(u >> 16);
            }
            if (tid < 64) Msk[tid] = (mp[k0 + tid] != 0) ? 1.f : 0.f;
        }
        __syncthreads();

        // QK^T (swapped, permuted rows): p[t2][r] = S[q = wave q-strip][key(t2,g,r)]
        bf16x8 bq = *(const bf16x8*)&Qs[(wid * 16 + r15) * 32 + g * 8];
        float p[4][4];
        float rmax = -3e38f;
        #pragma unroll
        for (int t2 = 0; t2 < 4; ++t2) {
            const int base = 32 * (t2 >> 1) + 4 * (t2 & 1);
            const int arow = base + 8 * (r15 >> 2) + (r15 & 3);
            bf16x8 ak = *(const bf16x8*)&Ks[arow * 32 + g * 8];
            f32x4 st = __builtin_amdgcn_mfma_f32_16x16x32_bf16(ak, bq, (f32x4){0.f, 0.f, 0.f, 0.f}, 0, 0, 0);
            #pragma unroll
            for (int r = 0; r < 4; ++r) {
                float mv = Msk[base + 8 * g + r];
                float v = (mv != 0.f) ? -1e9f : st[r] * scale;
                p[t2][r] = v;
                rmax = fmaxf(rmax, v);
            }
        }
        rmax = fmaxf(rmax, __shfl_xor(rmax, 16, 64));
        rmax = fmaxf(rmax, __shfl_xor(rmax, 32, 64));
        float mnew = fmaxf(mrun, rmax);
        float fs = __expf(mrun - mnew);
        mrun = mnew;
        lrun *= fs;
        accO[0] *= fs;
        accO[1] *= fs;
        float psum = 0.f;
        #pragma unroll
        for (int t2 = 0; t2 < 4; ++t2)
            #pragma unroll
            for (int r = 0; r < 4; ++r) {
                float e = __expf(p[t2][r] - mnew);
                p[t2][r] = e;
                psum += e;
            }
        psum += __shfl_xor(psum, 16, 64);
        psum += __shfl_xor(psum, 32, 64);
        lrun += psum;

        // pack P to bf16; lane already holds exactly its B-frag keys
        int pk[4][2];
        #pragma unroll
        for (int t2 = 0; t2 < 4; ++t2)
            #pragma unroll
            for (int rr = 0; rr < 2; ++rr)
                pk[t2][rr] = (int)(f2bf(p[t2][2 * rr]) | ((unsigned)f2bf(p[t2][2 * rr + 1]) << 16));
        i32x4 b0i = {pk[0][0], pk[0][1], pk[1][0], pk[1][1]};   // keys 0..31 (this lane's slice)
        i32x4 b1i = {pk[2][0], pk[2][1], pk[3][0], pk[3][1]};   // keys 32..63
        bf16x8 pb0 = __builtin_bit_cast(bf16x8, b0i);
        bf16x8 pb1 = __builtin_bit_cast(bf16x8, b1i);

        // PV: accO[mt] (O^T tile, d rows) += V^T x P^T
        #pragma unroll
        for (int mt = 0; mt < 2; ++mt) {
            bf16x8 av0 = *(const bf16x8*)&VsT[(mt * 16 + r15) * 72 + 8 * g];
            bf16x8 av1 = *(const bf16x8*)&VsT[(mt * 16 + r15) * 72 + 32 + 8 * g];
            accO[mt] = __builtin_amdgcn_mfma_f32_16x16x32_bf16(av0, pb0, accO[mt], 0, 0, 0);
            accO[mt] = __builtin_amdgcn_mfma_f32_16x16x32_bf16(av1, pb1, accO[mt], 0, 0, 0);
        }
    }

    const float inv = 1.f / lrun;
    const size_t orow = (size_t)bn * 512 + qt * 64 + wid * 16 + r15;
    #pragma unroll
    for (int mt = 0; mt < 2; ++mt) {
        ushort4 o;
        o.x = f2bf(accO[mt][0] * inv);
        o.y = f2bf(accO[mt][1] * inv);
        o.z = f2bf(accO[mt][2] * inv);
        o.w = f2bf(accO[mt][3] * inv);
        *(ushort4*)&ctx[orow * 256 + h * 32 + mt * 16 + 4 * g] = o;
    }
}

extern "C" void kernel_launch(void* const* d_in, const int* in_sizes, int n_in,
                              void* d_out, int out_size, void* d_ws, size_t ws_size,
                              hipStream_t stream) {
    const float* query = (const float*)d_in[0];
    const float* key   = (const float*)d_in[1];
    const float* value = (const float*)d_in[2];
    const int*   kpm   = (const int*)d_in[3];
    const float* w_pos = (const float*)d_in[4];
    const float* b_pos = (const float*)d_in[5];
    const float* w_vel = (const float*)d_in[6];
    const float* w_acc = (const float*)d_in[7];
    const float* Wq    = (const float*)d_in[8];
    const float* bq    = (const float*)d_in[9];
    const float* Wk    = (const float*)d_in[10];
    const float* bk    = (const float*)d_in[11];
    const float* Wv    = (const float*)d_in[12];
    const float* bv    = (const float*)d_in[13];
    const float* Wo    = (const float*)d_in[14];
    const float* bo    = (const float*)d_in[15];

    unsigned char* w = (unsigned char*)d_ws;
    unsigned short* XPQ = (unsigned short*)(w + OFF_XPQ);
    unsigned short* XPK = (unsigned short*)(w + OFF_XPK);
    unsigned short* VB  = (unsigned short*)(w + OFF_VB);
    unsigned short* BTQ = (unsigned short*)(w + OFF_BTQ);
    unsigned short* BTK = (unsigned short*)(w + OFF_BTK);
    float*          BEFF= (float*)(w + OFF_BEFF);
    unsigned short* WVT = (unsigned short*)(w + OFF_WVT);
    unsigned short* WOT = (unsigned short*)(w + OFF_WOT);
    unsigned short* QB  = (unsigned short*)(w + OFF_QB);
    unsigned short* KB  = (unsigned short*)(w + OFF_KB);
    unsigned short* VV  = (unsigned short*)(w + OFF_VV);
    unsigned short* CTX = (unsigned short*)(w + OFF_CTX);

    cvt_pad<<<4112, 256, 0, stream>>>(query, key, XPQ, XPK);
    cvt_v<<<2048, 256, 0, stream>>>(value, VB);
    eff_mats<<<1536, 256, 0, stream>>>(Wq, Wk, w_pos, w_vel, w_acc, BTQ, BTK);
    eff_bias<<<2, 256, 0, stream>>>(Wq, Wk, bq, bk, b_pos, BEFF);
    wconv<<<512, 256, 0, stream>>>(Wv, Wo, WVT, WOT);

    gemm_mfma<768, true, 255, unsigned short><<<dim3(256, 4), 256, 0, stream>>>(XPQ, BTQ, BEFF, QB);
    gemm_mfma<768, true, 255, unsigned short><<<dim3(256, 4), 256, 0, stream>>>(XPK, BTK, BEFF + 256, KB);
    gemm_mfma<256, false, 255, unsigned short><<<dim3(256, 4), 256, 0, stream>>>(VB, WVT, bv, VV);

    attn_mfma<<<dim3(8, 256), 256, 0, stream>>>(QB, KB, VV, kpm, CTX);

    gemm_mfma<512, false, 255, float><<<dim3(256, 4), 256, 0, stream>>>(CTX, WOT, bo, (float*)d_out);
}

// Round 3
// 101.819 us; speedup vs baseline: 4.6636x; 1.1484x over previous
//
#include <hip/hip_runtime.h>
#include <math.h>

// B=4, N=8, T=512, D=256, H=8, DK=32. BN=32, ROWS=16384.
// Full-bf16 MFMA pipeline, fp32 accumulate. Wo split hi/lo.
// R3: BK=64 swizzled GEMMs, dbuf attention w/ exp2 softmax, fused prep/cvt.

typedef __attribute__((ext_vector_type(8))) short bf16x8;
typedef __attribute__((ext_vector_type(4))) float f32x4;
typedef __attribute__((ext_vector_type(4))) int i32x4;

__device__ __forceinline__ unsigned short f2bf(float f) {
    unsigned u = __float_as_uint(f);
    return (unsigned short)((u + 0x7fff + ((u >> 16) & 1)) >> 16);
}
__device__ __forceinline__ float bf2f(unsigned short h) {
    return __uint_as_float(((unsigned)h) << 16);
}
__device__ __forceinline__ float ex2(float x) {         // v_exp_f32 = 2^x
    float r; asm("v_exp_f32 %0, %1" : "=v"(r) : "v"(x)); return r;
}
__device__ __forceinline__ int cvtpk(float lo, float hi) {  // bf16(lo) | bf16(hi)<<16, RNE
    int r; asm("v_cvt_pk_bf16_f32 %0, %1, %2" : "=v"(r) : "v"(lo), "v"(hi)); return r;
}
__device__ __forceinline__ void gll16(const void* gsrc, const void* ldst) {
    __builtin_amdgcn_global_load_lds(
        (const __attribute__((address_space(1))) unsigned int*)gsrc,
        (__attribute__((address_space(3))) unsigned int*)ldst, 16, 0, 0);
}

// scale(1/sqrt(32)) * log2(e): folded into Q projection -> softmax in exp2 domain
#define SCL (0.17677669529663689f * 1.4426950408889634f)

// ---- workspace byte offsets ----
#define OFF_XPQ  0u           // 32*514*256 bf16
#define OFF_XPK  8421376u
#define OFF_VB   16842752u    // 16384*256 bf16
#define OFF_BTQ  25231360u    // 256*768 bf16
#define OFF_BTK  25624576u
#define OFF_BEFF 26017792u    // 2*256 f32
#define OFF_WVT  26019840u    // 256*256 bf16
#define OFF_WOT  26150912u    // 256*512 bf16 (hi|lo)
#define OFF_QB   26413056u    // 16384*256 bf16
#define OFF_KB   34801664u
#define OFF_VV   43190272u
#define OFF_CTX  51578880u

// ---------------- fused input conversion: pad Q,K -> [32][514][256] bf16; V -> bf16 ----------------
__global__ __launch_bounds__(256) void cvt_all(const float* __restrict__ q,
                                               const float* __restrict__ k,
                                               const float* __restrict__ v,
                                               unsigned short* __restrict__ xpq,
                                               unsigned short* __restrict__ xpk,
                                               unsigned short* __restrict__ vb) {
    int bid = blockIdx.x;
    if (bid < 4112) {                       // padded q/k copies
        int idx = bid * 256 + threadIdx.x;  // 2 * 32*514*32
        int which = idx / 526336;
        int r = idx - which * 526336;
        int bn = r / 16448;
        int rr = r - bn * 16448;
        int p = rr >> 5;
        int c8 = (rr & 31) * 8;
        const float* src = which ? k : q;
        unsigned short* dst = which ? xpk : xpq;
        unsigned o[4] = {0, 0, 0, 0};
        if (p != 0 && p != 513) {
            const float* s = src + ((size_t)(bn * 512 + p - 1) * 256 + c8);
            float4 a = *(const float4*)s;
            float4 b = *(const float4*)(s + 4);
            o[0] = f2bf(a.x) | ((unsigned)f2bf(a.y) << 16);
            o[1] = f2bf(a.z) | ((unsigned)f2bf(a.w) << 16);
            o[2] = f2bf(b.x) | ((unsigned)f2bf(b.y) << 16);
            o[3] = f2bf(b.z) | ((unsigned)f2bf(b.w) << 16);
        }
        unsigned* d = (unsigned*)(dst + ((size_t)(bn * 514 + p) * 256 + c8));
        d[0] = o[0]; d[1] = o[1]; d[2] = o[2]; d[3] = o[3];
    } else {                                // v conversion
        int idx = (bid - 4112) * 256 + threadIdx.x;   // 16384*32
        int row = idx >> 5;
        int c8 = (idx & 31) * 8;
        const float* s = v + ((size_t)row * 256 + c8);
        float4 a = *(const float4*)s;
        float4 b = *(const float4*)(s + 4);
        unsigned* d = (unsigned*)(vb + ((size_t)row * 256 + c8));
        d[0] = f2bf(a.x) | ((unsigned)f2bf(a.y) << 16);
        d[1] = f2bf(a.z) | ((unsigned)f2bf(a.w) << 16);
        d[2] = f2bf(b.x) | ((unsigned)f2bf(b.y) << 16);
        d[3] = f2bf(b.z) | ((unsigned)f2bf(b.w) << 16);
    }
}

// ---------------- fused weight prep ----------------
// blocks 0..1535: folded conv mats (Q side pre-scaled by SCL)
// blocks 1536..2047: Wv transpose + Wo hi/lo transpose
// blocks 2048..2049: effective biases
__global__ __launch_bounds__(256) void prep(const float* __restrict__ Wq,
                                            const float* __restrict__ Wk,
                                            const float* __restrict__ bq,
                                            const float* __restrict__ bk,
                                            const float* __restrict__ wp,
                                            const float* __restrict__ wv,
                                            const float* __restrict__ wa,
                                            const float* __restrict__ b_pos,
                                            const float* __restrict__ Wv,
                                            const float* __restrict__ Wo,
                                            unsigned short* __restrict__ BtQ,
                                            unsigned short* __restrict__ BtK,
                                            float* __restrict__ beff,
                                            unsigned short* __restrict__ WVT,
                                            unsigned short* __restrict__ WOT) {
    int bid = blockIdx.x;
    if (bid < 1536) {
        int idx = bid * 256 + threadIdx.x;   // 2*3*256*256
        int which = idx / 196608;
        int r = idx - which * 196608;
        int j = r >> 16;
        int rem = r & 65535;
        int n = rem >> 8;
        int d = rem & 255;
        const float* W = which ? Wk : Wq;
        float val = wp[d * 3 + j] * W[d * 256 + n]
                  + wv[d * 3 + j] * W[(256 + d) * 256 + n]
                  + wa[d * 3 + j] * W[(512 + d) * 256 + n];
        if (!which) val *= SCL;
        (which ? BtK : BtQ)[n * 768 + j * 256 + d] = f2bf(val);
    } else if (bid < 2048) {
        int idx = (bid - 1536) * 256 + threadIdx.x;   // 2*65536
        int which = idx >> 16;
        int r = idx & 65535;
        int n = r >> 8, k = r & 255;
        if (!which) {
            WVT[n * 256 + k] = f2bf(Wv[k * 256 + n]);
        } else {
            float v = Wo[k * 256 + n];
            unsigned short hi = f2bf(v);
            WOT[n * 512 + k] = hi;
            WOT[n * 512 + 256 + k] = f2bf(v - bf2f(hi));
        }
    } else {
        int which = bid - 2048;
        int n = threadIdx.x;
        const float* W = which ? Wk : Wq;
        const float* bb = which ? bk : bq;
        float s = bb[n];
        for (int d = 0; d < 256; ++d) s = fmaf(b_pos[d], W[d * 256 + n], s);
        if (!which) s *= SCL;
        beff[which * 256 + n] = s;
    }
}

// ---------------- MFMA GEMM: [16384 x KTOT] x [KTOT x 256] + bias, BK=64, swizzled LDS ----------------
// LDS rows = 64 shorts (128 B, 8 chunks); chunk stored at c holds source chunk c^(row&7)
// (pre-swizzled global source, linear gll16 dest). Fragment reads are 2-way (free).
template<int KTOT, bool IM2COL, int AMASK, typename OutT>
__global__ __launch_bounds__(256) void gemm_mfma(const unsigned short* __restrict__ A,
                                                 const unsigned short* __restrict__ Bt,
                                                 const float* __restrict__ bias,
                                                 OutT* __restrict__ Out) {
    __shared__ alignas(16) unsigned short As[64 * 64];
    __shared__ alignas(16) unsigned short Bs[64 * 64];
    const int tid = threadIdx.x;
    const int wid = tid >> 6, l = tid & 63;
    const int g = l >> 4, r15 = l & 15;
    const int wm = wid >> 1, wn = wid & 1;
    const int m0 = blockIdx.x * 64, n0 = blockIdx.y * 64;

    // staging mapping: call q covers chunks cidx = q*256 + wid*64 + l
    int rowq[2], colq[2];
    #pragma unroll
    for (int q = 0; q < 2; ++q) {
        int cidx = q * 256 + wid * 64 + l;
        rowq[q] = cidx >> 3;
        colq[q] = ((cidx & 7) ^ (rowq[q] & 7)) * 8;   // pre-swizzled source chunk
    }

    f32x4 acc[2][2] = {};
    for (int k0 = 0; k0 < KTOT; k0 += 64) {
        __syncthreads();
        #pragma unroll
        for (int q = 0; q < 2; ++q) {
            const unsigned short* asrc;
            if (IM2COL) {
                const int seq = m0 >> 9, t0 = m0 & 511;
                const int j = k0 >> 8, c0 = k0 & 255;
                asrc = A + ((size_t)(seq * 514 + t0 + rowq[q] + j) * 256 + c0 + colq[q]);
            } else {
                asrc = A + ((size_t)(m0 + rowq[q]) * (AMASK + 1) + (((k0 & AMASK)) + colq[q]));
            }
            gll16(asrc, As + q * 2048 + wid * 512);
            gll16(Bt + ((size_t)(n0 + rowq[q]) * KTOT + k0 + colq[q]), Bs + q * 2048 + wid * 512);
        }
        __syncthreads();

        #pragma unroll
        for (int s = 0; s < 2; ++s) {
            const int ch = ((s * 4 + g) ^ (r15 & 7)) * 8;
            bf16x8 af0 = *(const bf16x8*)&As[(wm * 32 + r15) * 64 + ch];
            bf16x8 af1 = *(const bf16x8*)&As[(wm * 32 + 16 + r15) * 64 + ch];
            bf16x8 bf0 = *(const bf16x8*)&Bs[(wn * 32 + r15) * 64 + ch];
            bf16x8 bf1 = *(const bf16x8*)&Bs[(wn * 32 + 16 + r15) * 64 + ch];
            acc[0][0] = __builtin_amdgcn_mfma_f32_16x16x32_bf16(af0, bf0, acc[0][0], 0, 0, 0);
            acc[0][1] = __builtin_amdgcn_mfma_f32_16x16x32_bf16(af0, bf1, acc[0][1], 0, 0, 0);
            acc[1][0] = __builtin_amdgcn_mfma_f32_16x16x32_bf16(af1, bf0, acc[1][0], 0, 0, 0);
            acc[1][1] = __builtin_amdgcn_mfma_f32_16x16x32_bf16(af1, bf1, acc[1][1], 0, 0, 0);
        }
    }

    #pragma unroll
    for (int nt = 0; nt < 2; ++nt) {
        const int col = n0 + wn * 32 + nt * 16 + r15;
        const float bb = bias[col];
        #pragma unroll
        for (int mt = 0; mt < 2; ++mt) {
            #pragma unroll
            for (int r = 0; r < 4; ++r) {
                const size_t row = m0 + wm * 32 + mt * 16 + 4 * g + r;
                float v = acc[mt][nt][r] + bb;
                if constexpr (sizeof(OutT) == 2) Out[row * 256 + col] = (OutT)f2bf(v);
                else Out[row * 256 + col] = (OutT)v;
            }
        }
    }
}

// ---------------- fused MFMA flash attention (dbuf, single barrier per tile) ----------------
__global__ __launch_bounds__(256) void attn_mfma(const unsigned short* __restrict__ Qb,
                                                 const unsigned short* __restrict__ Kb,
                                                 const unsigned short* __restrict__ Vv,
                                                 const int* __restrict__ mask,
                                                 unsigned short* __restrict__ ctx) {
    __shared__ alignas(16) unsigned short Qs[64 * 32];       // linear
    __shared__ alignas(16) unsigned short Ks[2][64 * 32];    // chunk-xor (c ^ (row&3))
    __shared__ alignas(16) unsigned short VsT[2][32 * 72];   // [d][key], padded
    __shared__ float Mb[2][64];                              // additive mask bias

    const int qt = blockIdx.x, bnh = blockIdx.y;
    const int bn = bnh >> 3, h = bnh & 7;
    const int tid = threadIdx.x, wid = tid >> 6, l = tid & 63;
    const int g = l >> 4, r15 = l & 15;
    const unsigned short* Qg = Qb + (size_t)bn * 512 * 256 + h * 32;
    const unsigned short* Kg = Kb + (size_t)bn * 512 * 256 + h * 32;
    const unsigned short* Vg = Vv + (size_t)bn * 512 * 256 + h * 32;
    const int* mp = mask + bn * 512;
    const int drow = tid >> 2;
    const int kc8 = (((tid & 3) ^ (drow & 3))) * 8;   // pre-swizzled K source col
    const int qc8 = (tid & 3) * 8;                    // linear Q source col
    const int key = tid & 63, d0 = (tid >> 6) * 8;    // V staging coords

    // ---- prologue: stage Q, K0, V0, Mb0 ----
    gll16(Qg + ((size_t)(qt * 64 + drow)) * 256 + qc8, Qs + wid * 512);
    gll16(Kg + (size_t)drow * 256 + kc8, Ks[0] + wid * 512);
    {
        i32x4 v0 = *(const i32x4*)(const void*)(Vg + (size_t)key * 256 + d0);
        #pragma unroll
        for (int i = 0; i < 4; ++i) {
            unsigned u = (unsigned)v0[i];
            VsT[0][(d0 + 2 * i) * 72 + key] = (unsigned short)(u & 0xffff);
            VsT[0][(d0 + 2 * i + 1) * 72 + key] = (unsigned short)(u >> 16);
        }
        if (tid < 64) Mb[0][tid] = (mp[tid] != 0) ? -1e9f : 0.f;
    }
    __syncthreads();

    const bf16x8 bq = *(const bf16x8*)&Qs[(wid * 16 + r15) * 32 + g * 8];   // hoisted Q frag

    float mrun = -1e30f, lrun = 0.f;
    f32x4 accO[2] = {};

    for (int kt = 0; kt < 8; ++kt) {
        const int cur = kt & 1, nxt = cur ^ 1;
        const int k0n = kt * 64 + 64;

        // ---- issue next-tile loads early (overlap with compute) ----
        i32x4 vld;
        int mraw = 0;
        if (kt < 7) {
            gll16(Kg + ((size_t)(k0n + drow)) * 256 + kc8, Ks[nxt] + wid * 512);
            vld = *(const i32x4*)(const void*)(Vg + ((size_t)(k0n + key)) * 256 + d0);
            if (tid < 64) mraw = mp[k0n + tid];
        }

        // ---- QK^T (swapped, permuted A rows) ----
        float p[4][4];
        float rmax = -3e38f;
        #pragma unroll
        for (int t2 = 0; t2 < 4; ++t2) {
            const int base = 32 * (t2 >> 1) + 4 * (t2 & 1);
            const int arow = base + 8 * (r15 >> 2) + (r15 & 3);
            bf16x8 ak = *(const bf16x8*)&Ks[cur][arow * 32 + ((g ^ (arow & 3)) * 8)];
            f32x4 st = __builtin_amdgcn_mfma_f32_16x16x32_bf16(ak, bq, (f32x4){0.f, 0.f, 0.f, 0.f}, 0, 0, 0);
            #pragma unroll
            for (int r = 0; r < 4; ++r) {
                float v = st[r] + Mb[cur][base + 8 * g + r];   // scale*log2e pre-folded into Q
                p[t2][r] = v;
                rmax = fmaxf(rmax, v);
            }
        }
        rmax = fmaxf(rmax, __shfl_xor(rmax, 16, 64));
        rmax = fmaxf(rmax, __shfl_xor(rmax, 32, 64));

        if (__ballot(rmax > mrun)) {          // defer-max: skip rescale when no lane improves
            float mnew = fmaxf(mrun, rmax);
            float fs = ex2(mrun - mnew);
            lrun *= fs;
            accO[0] *= fs;
            accO[1] *= fs;
            mrun = mnew;
        }
        float psum = 0.f;
        #pragma unroll
        for (int t2 = 0; t2 < 4; ++t2)
            #pragma unroll
            for (int r = 0; r < 4; ++r) {
                float e = ex2(p[t2][r] - mrun);
                p[t2][r] = e;
                psum += e;
            }
        psum += __shfl_xor(psum, 16, 64);
        psum += __shfl_xor(psum, 32, 64);
        lrun += psum;

        // ---- pack P (lane already holds its PV B-frag keys) ----
        i32x4 b0i = {cvtpk(p[0][0], p[0][1]), cvtpk(p[0][2], p[0][3]),
                     cvtpk(p[1][0], p[1][1]), cvtpk(p[1][2], p[1][3])};
        i32x4 b1i = {cvtpk(p[2][0], p[2][1]), cvtpk(p[2][2], p[2][3]),
                     cvtpk(p[3][0], p[3][1]), cvtpk(p[3][2], p[3][3])};
        bf16x8 pb0 = __builtin_bit_cast(bf16x8, b0i);
        bf16x8 pb1 = __builtin_bit_cast(bf16x8, b1i);

        // ---- PV: accO (O^T tile) += V^T x P^T ----
        #pragma unroll
        for (int mt = 0; mt < 2; ++mt) {
            bf16x8 av0 = *(const bf16x8*)&VsT[cur][(mt * 16 + r15) * 72 + 8 * g];
            bf16x8 av1 = *(const bf16x8*)&VsT[cur][(mt * 16 + r15) * 72 + 32 + 8 * g];
            accO[mt] = __builtin_amdgcn_mfma_f32_16x16x32_bf16(av0, pb0, accO[mt], 0, 0, 0);
            accO[mt] = __builtin_amdgcn_mfma_f32_16x16x32_bf16(av1, pb1, accO[mt], 0, 0, 0);
        }

        // ---- write-late: V(kt+1) regs -> LDS, mask bias ----
        if (kt < 7) {
            #pragma unroll
            for (int i = 0; i < 4; ++i) {
                unsigned u = (unsigned)vld[i];
                VsT[nxt][(d0 + 2 * i) * 72 + key] = (unsigned short)(u & 0xffff);
                VsT[nxt][(d0 + 2 * i + 1) * 72 + key] = (unsigned short)(u >> 16);
            }
            if (tid < 64) Mb[nxt][tid] = (mraw != 0) ? -1e9f : 0.f;
        }
        __syncthreads();   // drains gll16 (vmcnt) + ds_writes; next iter flips buffers
    }

    const float inv = 1.f / lrun;
    const size_t orow = (size_t)bn * 512 + qt * 64 + wid * 16 + r15;
    #pragma unroll
    for (int mt = 0; mt < 2; ++mt) {
        ushort4 o;
        o.x = f2bf(accO[mt][0] * inv);
        o.y = f2bf(accO[mt][1] * inv);
        o.z = f2bf(accO[mt][2] * inv);
        o.w = f2bf(accO[mt][3] * inv);
        *(ushort4*)&ctx[orow * 256 + h * 32 + mt * 16 + 4 * g] = o;
    }
}

extern "C" void kernel_launch(void* const* d_in, const int* in_sizes, int n_in,
                              void* d_out, int out_size, void* d_ws, size_t ws_size,
                              hipStream_t stream) {
    const float* query = (const float*)d_in[0];
    const float* key   = (const float*)d_in[1];
    const float* value = (const float*)d_in[2];
    const int*   kpm   = (const int*)d_in[3];
    const float* w_pos = (const float*)d_in[4];
    const float* b_pos = (const float*)d_in[5];
    const float* w_vel = (const float*)d_in[6];
    const float* w_acc = (const float*)d_in[7];
    const float* Wq    = (const float*)d_in[8];
    const float* bq    = (const float*)d_in[9];
    const float* Wk    = (const float*)d_in[10];
    const float* bk    = (const float*)d_in[11];
    const float* Wv    = (const float*)d_in[12];
    const float* bv    = (const float*)d_in[13];
    const float* Wo    = (const float*)d_in[14];
    const float* bo    = (const float*)d_in[15];

    unsigned char* w = (unsigned char*)d_ws;
    unsigned short* XPQ = (unsigned short*)(w + OFF_XPQ);
    unsigned short* XPK = (unsigned short*)(w + OFF_XPK);
    unsigned short* VB  = (unsigned short*)(w + OFF_VB);
    unsigned short* BTQ = (unsigned short*)(w + OFF_BTQ);
    unsigned short* BTK = (unsigned short*)(w + OFF_BTK);
    float*          BEFF= (float*)(w + OFF_BEFF);
    unsigned short* WVT = (unsigned short*)(w + OFF_WVT);
    unsigned short* WOT = (unsigned short*)(w + OFF_WOT);
    unsigned short* QB  = (unsigned short*)(w + OFF_QB);
    unsigned short* KB  = (unsigned short*)(w + OFF_KB);
    unsigned short* VV  = (unsigned short*)(w + OFF_VV);
    unsigned short* CTX = (unsigned short*)(w + OFF_CTX);

    cvt_all<<<6160, 256, 0, stream>>>(query, key, value, XPQ, XPK, VB);
    prep<<<2050, 256, 0, stream>>>(Wq, Wk, bq, bk, w_pos, w_vel, w_acc, b_pos,
                                   Wv, Wo, BTQ, BTK, BEFF, WVT, WOT);

    gemm_mfma<768, true, 255, unsigned short><<<dim3(256, 4), 256, 0, stream>>>(XPQ, BTQ, BEFF, QB);
    gemm_mfma<768, true, 255, unsigned short><<<dim3(256, 4), 256, 0, stream>>>(XPK, BTK, BEFF + 256, KB);
    gemm_mfma<256, false, 255, unsigned short><<<dim3(256, 4), 256, 0, stream>>>(VB, WVT, bv, VV);

    attn_mfma<<<dim3(8, 256), 256, 0, stream>>>(QB, KB, VV, kpm, CTX);

    gemm_mfma<512, false, 255, float><<<dim3(256, 4), 256, 0, stream>>>(CTX, WOT, bo, (float*)d_out);
}

// Round 4
// 96.665 us; speedup vs baseline: 4.9122x; 1.0533x over previous
//
#include <hip/hip_runtime.h>
#include <math.h>

// B=4, N=8, T=512, D=256, H=8, DK=32. BN=32, ROWS=16384.
// R4: dbuf 64x128 GEMM (one fused proj launch), KVBLK=128 attention, 4 launches.

typedef __attribute__((ext_vector_type(8))) short bf16x8;
typedef __attribute__((ext_vector_type(4))) float f32x4;
typedef __attribute__((ext_vector_type(4))) int i32x4;

__device__ __forceinline__ unsigned short f2bf(float f) {
    unsigned u = __float_as_uint(f);
    return (unsigned short)((u + 0x7fff + ((u >> 16) & 1)) >> 16);
}
__device__ __forceinline__ float bf2f(unsigned short h) {
    return __uint_as_float(((unsigned)h) << 16);
}
__device__ __forceinline__ float ex2(float x) {
    float r; asm("v_exp_f32 %0, %1" : "=v"(r) : "v"(x)); return r;
}
__device__ __forceinline__ int cvtpk(float lo, float hi) {
    int r; asm("v_cvt_pk_bf16_f32 %0, %1, %2" : "=v"(r) : "v"(lo), "v"(hi)); return r;
}
__device__ __forceinline__ void gll16(const void* gsrc, const void* ldst) {
    __builtin_amdgcn_global_load_lds(
        (const __attribute__((address_space(1))) unsigned int*)gsrc,
        (__attribute__((address_space(3))) unsigned int*)ldst, 16, 0, 0);
}

// scale(1/sqrt(32)) * log2(e): folded into Q projection -> softmax in exp2 domain
#define SCL (0.17677669529663689f * 1.4426950408889634f)

// ---- workspace byte offsets ----
#define OFF_XPQ  0u
#define OFF_XPK  8421376u
#define OFF_VB   16842752u
#define OFF_BTQ  25231360u
#define OFF_BTK  25624576u
#define OFF_BEFF 26017792u
#define OFF_WVT  26019840u
#define OFF_WOT  26150912u
#define OFF_QB   26413056u
#define OFF_KB   34801664u
#define OFF_VV   43190272u
#define OFF_CTX  51578880u

// ---------------- fused conversion + weight prep (one launch) ----------------
__global__ __launch_bounds__(256) void cvtprep(
    const float* __restrict__ q, const float* __restrict__ k, const float* __restrict__ v,
    unsigned short* __restrict__ xpq, unsigned short* __restrict__ xpk,
    unsigned short* __restrict__ vb,
    const float* __restrict__ Wq, const float* __restrict__ Wk,
    const float* __restrict__ bq, const float* __restrict__ bk,
    const float* __restrict__ wp, const float* __restrict__ wv,
    const float* __restrict__ wa, const float* __restrict__ b_pos,
    const float* __restrict__ Wv, const float* __restrict__ Wo,
    unsigned short* __restrict__ BtQ, unsigned short* __restrict__ BtK,
    float* __restrict__ beff, unsigned short* __restrict__ WVT,
    unsigned short* __restrict__ WOT)
{
    int bid = blockIdx.x;
    if (bid < 4112) {                       // padded q/k conversion
        int idx = bid * 256 + threadIdx.x;
        int which = idx / 526336;
        int r = idx - which * 526336;
        int bn = r / 16448;
        int rr = r - bn * 16448;
        int p = rr >> 5;
        int c8 = (rr & 31) * 8;
        const float* src = which ? k : q;
        unsigned short* dst = which ? xpk : xpq;
        unsigned o[4] = {0, 0, 0, 0};
        if (p != 0 && p != 513) {
            const float* s = src + ((size_t)(bn * 512 + p - 1) * 256 + c8);
            float4 a = *(const float4*)s;
            float4 b = *(const float4*)(s + 4);
            o[0] = f2bf(a.x) | ((unsigned)f2bf(a.y) << 16);
            o[1] = f2bf(a.z) | ((unsigned)f2bf(a.w) << 16);
            o[2] = f2bf(b.x) | ((unsigned)f2bf(b.y) << 16);
            o[3] = f2bf(b.z) | ((unsigned)f2bf(b.w) << 16);
        }
        unsigned* d = (unsigned*)(dst + ((size_t)(bn * 514 + p) * 256 + c8));
        d[0] = o[0]; d[1] = o[1]; d[2] = o[2]; d[3] = o[3];
    } else if (bid < 6160) {                // v conversion
        int idx = (bid - 4112) * 256 + threadIdx.x;
        int row = idx >> 5;
        int c8 = (idx & 31) * 8;
        const float* s = v + ((size_t)row * 256 + c8);
        float4 a = *(const float4*)s;
        float4 b = *(const float4*)(s + 4);
        unsigned* d = (unsigned*)(vb + ((size_t)row * 256 + c8));
        d[0] = f2bf(a.x) | ((unsigned)f2bf(a.y) << 16);
        d[1] = f2bf(a.z) | ((unsigned)f2bf(a.w) << 16);
        d[2] = f2bf(b.x) | ((unsigned)f2bf(b.y) << 16);
        d[3] = f2bf(b.z) | ((unsigned)f2bf(b.w) << 16);
    } else if (bid < 7696) {                // folded conv mats
        int idx = (bid - 6160) * 256 + threadIdx.x;
        int which = idx / 196608;
        int r = idx - which * 196608;
        int j = r >> 16;
        int rem = r & 65535;
        int n = rem >> 8;
        int d = rem & 255;
        const float* W = which ? Wk : Wq;
        float val = wp[d * 3 + j] * W[d * 256 + n]
                  + wv[d * 3 + j] * W[(256 + d) * 256 + n]
                  + wa[d * 3 + j] * W[(512 + d) * 256 + n];
        if (!which) val *= SCL;
        (which ? BtK : BtQ)[n * 768 + j * 256 + d] = f2bf(val);
    } else if (bid < 8208) {                // Wv / Wo transposes
        int idx = (bid - 7696) * 256 + threadIdx.x;
        int which = idx >> 16;
        int r = idx & 65535;
        int n = r >> 8, kk = r & 255;
        if (!which) {
            WVT[n * 256 + kk] = f2bf(Wv[kk * 256 + n]);
        } else {
            float vv = Wo[kk * 256 + n];
            unsigned short hi = f2bf(vv);
            WOT[n * 512 + kk] = hi;
            WOT[n * 512 + 256 + kk] = f2bf(vv - bf2f(hi));
        }
    } else {                                // effective biases
        int which = bid - 8208;
        int n = threadIdx.x;
        const float* W = which ? Wk : Wq;
        const float* bb = which ? bk : bq;
        float s = bb[n];
        for (int d = 0; d < 256; ++d) s = fmaf(b_pos[d], W[d * 256 + n], s);
        if (!which) s *= SCL;
        beff[which * 256 + n] = s;
    }
}

// ---------------- dbuf MFMA GEMM body: 64M x 128N tile, BK=64 ----------------
// LDS rows = 64 shorts (8 chunks), chunk c holds source chunk c^(row&7)
// (pre-swizzled global source, linear gll16 dest). Single barrier per K-step.
template<typename OutT>
__device__ __forceinline__ void gemm_body(
    const unsigned short* __restrict__ A, const unsigned short* __restrict__ Bt,
    const float* __restrict__ bias, OutT* __restrict__ Out,
    int ktot, int btstride, int im2col,
    unsigned short* As, unsigned short* Bs)
{
    const int tid = threadIdx.x;
    const int wid = tid >> 6, l = tid & 63;
    const int g = l >> 4, r15 = l & 15;
    const int wm = wid & 1, wn = wid >> 1;
    const int m0 = blockIdx.x * 64, n0 = blockIdx.y * 128;

    f32x4 acc[2][4] = {};

    auto stage = [&](int k0, int b) {
        unsigned short* as = As + b * 4096;
        unsigned short* bs = Bs + b * 8192;
        #pragma unroll
        for (int qq = 0; qq < 2; ++qq) {
            int cidx = qq * 256 + wid * 64 + l;
            int row = cidx >> 3, csrc = ((cidx & 7) ^ (row & 7)) * 8;
            const unsigned short* src;
            if (im2col) {
                int seq = m0 >> 9, t0 = m0 & 511, j = k0 >> 8, c0 = k0 & 255;
                src = A + ((size_t)(seq * 514 + t0 + row + j) * 256 + c0 + csrc);
            } else {
                src = A + ((size_t)(m0 + row) * 256 + (k0 & 255) + csrc);
            }
            gll16(src, as + qq * 2048 + wid * 512);
        }
        #pragma unroll
        for (int qq = 0; qq < 4; ++qq) {
            int cidx = qq * 256 + wid * 64 + l;
            int row = cidx >> 3, csrc = ((cidx & 7) ^ (row & 7)) * 8;
            gll16(Bt + ((size_t)(n0 + row) * btstride + k0 + csrc), bs + qq * 2048 + wid * 512);
        }
    };

    stage(0, 0);
    __syncthreads();
    int b = 0;
    for (int k0 = 0; k0 < ktot; k0 += 64, b ^= 1) {
        if (k0 + 64 < ktot) stage(k0 + 64, b ^ 1);
        const unsigned short* as = As + b * 4096;
        const unsigned short* bs = Bs + b * 8192;
        #pragma unroll
        for (int s = 0; s < 2; ++s) {
            const int ch = ((s * 4 + g) ^ (r15 & 7)) * 8;
            bf16x8 af[2], bf[4];
            #pragma unroll
            for (int mt = 0; mt < 2; ++mt)
                af[mt] = *(const bf16x8*)&as[(wm * 32 + mt * 16 + r15) * 64 + ch];
            #pragma unroll
            for (int nt = 0; nt < 4; ++nt)
                bf[nt] = *(const bf16x8*)&bs[(wn * 64 + nt * 16 + r15) * 64 + ch];
            #pragma unroll
            for (int mt = 0; mt < 2; ++mt)
                #pragma unroll
                for (int nt = 0; nt < 4; ++nt)
                    acc[mt][nt] = __builtin_amdgcn_mfma_f32_16x16x32_bf16(af[mt], bf[nt], acc[mt][nt], 0, 0, 0);
        }
        __syncthreads();
    }

    #pragma unroll
    for (int nt = 0; nt < 4; ++nt) {
        const int col = n0 + wn * 64 + nt * 16 + r15;
        const float bb = bias[col];
        #pragma unroll
        for (int mt = 0; mt < 2; ++mt)
            #pragma unroll
            for (int r = 0; r < 4; ++r) {
                const size_t row = m0 + wm * 32 + mt * 16 + 4 * g + r;
                float vv = acc[mt][nt][r] + bb;
                if constexpr (sizeof(OutT) == 2) Out[row * 256 + col] = (OutT)f2bf(vv);
                else Out[row * 256 + col] = (OutT)vv;
            }
    }
}

// one launch for Q-proj (z=0), K-proj (z=1), V-proj (z=2)
__global__ __launch_bounds__(256) void proj_fused(
    const unsigned short* __restrict__ XPQ, const unsigned short* __restrict__ XPK,
    const unsigned short* __restrict__ VB,
    const unsigned short* __restrict__ BTQ, const unsigned short* __restrict__ BTK,
    const unsigned short* __restrict__ WVT,
    const float* __restrict__ BEFF, const float* __restrict__ bv,
    unsigned short* __restrict__ QB, unsigned short* __restrict__ KB,
    unsigned short* __restrict__ VV)
{
    __shared__ alignas(16) unsigned short As[2 * 4096];
    __shared__ alignas(16) unsigned short Bs[2 * 8192];
    const int z = blockIdx.z;
    const unsigned short* A  = z == 0 ? XPQ : (z == 1 ? XPK : VB);
    const unsigned short* Bt = z == 0 ? BTQ : (z == 1 ? BTK : WVT);
    const float* bias        = z == 0 ? BEFF : (z == 1 ? BEFF + 256 : bv);
    unsigned short* Out      = z == 0 ? QB : (z == 1 ? KB : VV);
    const int ktot = z < 2 ? 768 : 256;
    gemm_body<unsigned short>(A, Bt, bias, Out, ktot, ktot, z < 2 ? 1 : 0, As, Bs);
}

__global__ __launch_bounds__(256) void outproj(
    const unsigned short* __restrict__ CTX, const unsigned short* __restrict__ WOT,
    const float* __restrict__ bo, float* __restrict__ Out)
{
    __shared__ alignas(16) unsigned short As[2 * 4096];
    __shared__ alignas(16) unsigned short Bs[2 * 8192];
    gemm_body<float>(CTX, WOT, bo, Out, 512, 512, 0, As, Bs);
}

// ---------------- fused MFMA flash attention, KVBLK=128, dbuf ----------------
__global__ __launch_bounds__(256) void attn_mfma(const unsigned short* __restrict__ Qb,
                                                 const unsigned short* __restrict__ Kb,
                                                 const unsigned short* __restrict__ Vv,
                                                 const int* __restrict__ mask,
                                                 unsigned short* __restrict__ ctx) {
    __shared__ alignas(16) unsigned short Qs[64 * 32];
    __shared__ alignas(16) unsigned short Ks[2][128 * 32];   // chunk-xor (c ^ (row&3))
    __shared__ alignas(16) unsigned short VsT[2][32 * 136];  // [d][key], 17-chunk rows
    __shared__ float Mb[2][128];

    const int qt = blockIdx.x, bnh = blockIdx.y;
    const int bn = bnh >> 3, h = bnh & 7;
    const int tid = threadIdx.x, wid = tid >> 6, l = tid & 63;
    const int g = l >> 4, r15 = l & 15;
    const unsigned short* Qg = Qb + (size_t)bn * 512 * 256 + h * 32;
    const unsigned short* Kg = Kb + (size_t)bn * 512 * 256 + h * 32;
    const unsigned short* Vg = Vv + (size_t)bn * 512 * 256 + h * 32;
    const int* mp = mask + bn * 512;

    auto stageK = [&](int k0, int b) {
        #pragma unroll
        for (int qq = 0; qq < 2; ++qq) {
            int cidx = qq * 256 + wid * 64 + l;
            int row = cidx >> 2, csrc = ((cidx & 3) ^ (row & 3)) * 8;
            gll16(Kg + ((size_t)(k0 + row)) * 256 + csrc, &Ks[b][qq * 2048 + wid * 512]);
        }
    };

    // ---- prologue: Q, K0, V0, Mb0 ----
    {
        int cidx = wid * 64 + l;
        gll16(Qg + ((size_t)(qt * 64 + (cidx >> 2))) * 256 + (cidx & 3) * 8, Qs + wid * 512);
    }
    stageK(0, 0);
    {
        #pragma unroll
        for (int qq = 0; qq < 2; ++qq) {
            int key = l + 64 * qq;
            i32x4 vr = *(const i32x4*)(const void*)(Vg + (size_t)key * 256 + wid * 8);
            #pragma unroll
            for (int i = 0; i < 4; ++i) {
                unsigned u = (unsigned)vr[i];
                VsT[0][(wid * 8 + 2 * i) * 136 + key] = (unsigned short)(u & 0xffff);
                VsT[0][(wid * 8 + 2 * i + 1) * 136 + key] = (unsigned short)(u >> 16);
            }
        }
        if (tid < 128) Mb[0][tid] = (mp[tid] != 0) ? -1e9f : 0.f;
    }
    __syncthreads();

    const bf16x8 bq = *(const bf16x8*)&Qs[(wid * 16 + r15) * 32 + g * 8];

    float mrun = -1e30f, lrun = 0.f;
    f32x4 accO[2] = {};

    for (int kt = 0; kt < 4; ++kt) {
        const int cur = kt & 1, nxt = cur ^ 1;
        const int k0n = kt * 128 + 128;

        // ---- issue next-tile loads early ----
        i32x4 vr[2];
        int mraw = 0;
        if (kt < 3) {
            stageK(k0n, nxt);
            #pragma unroll
            for (int qq = 0; qq < 2; ++qq)
                vr[qq] = *(const i32x4*)(const void*)(Vg + ((size_t)(k0n + l + 64 * qq)) * 256 + wid * 8);
            if (tid < 128) mraw = mp[k0n + tid];
        }

        // ---- QK^T (swapped, permuted A rows), mask bias as MFMA C-in ----
        float p[8][4];
        float rmax = -3e38f;
        __builtin_amdgcn_s_setprio(1);
        #pragma unroll
        for (int t2 = 0; t2 < 8; ++t2) {
            const int base = 32 * (t2 >> 1) + 4 * (t2 & 1);
            const int arow = base + 8 * (r15 >> 2) + (r15 & 3);
            bf16x8 ak = *(const bf16x8*)&Ks[cur][arow * 32 + ((g ^ (arow & 3)) * 8)];
            f32x4 cin = *(const f32x4*)&Mb[cur][base + 8 * g];
            f32x4 st = __builtin_amdgcn_mfma_f32_16x16x32_bf16(ak, bq, cin, 0, 0, 0);
            #pragma unroll
            for (int r = 0; r < 4; ++r) p[t2][r] = st[r];
            rmax = fmaxf(rmax, fmaxf(fmaxf(st[0], st[1]), fmaxf(st[2], st[3])));
        }
        __builtin_amdgcn_s_setprio(0);
        rmax = fmaxf(rmax, __shfl_xor(rmax, 16, 64));
        rmax = fmaxf(rmax, __shfl_xor(rmax, 32, 64));

        if (__ballot(rmax > mrun)) {
            float mnew = fmaxf(mrun, rmax);
            float fs = ex2(mrun - mnew);
            lrun *= fs;
            accO[0] *= fs;
            accO[1] *= fs;
            mrun = mnew;
        }
        float psum = 0.f;
        #pragma unroll
        for (int t2 = 0; t2 < 8; ++t2)
            #pragma unroll
            for (int r = 0; r < 4; ++r) {
                float e = ex2(p[t2][r] - mrun);
                p[t2][r] = e;
                psum += e;
            }
        psum += __shfl_xor(psum, 16, 64);
        psum += __shfl_xor(psum, 32, 64);
        lrun += psum;

        // ---- pack P (lane holds exactly its PV B-frag keys) ----
        bf16x8 pb[4];
        #pragma unroll
        for (int s = 0; s < 4; ++s) {
            i32x4 bi = {cvtpk(p[2 * s][0], p[2 * s][1]), cvtpk(p[2 * s][2], p[2 * s][3]),
                        cvtpk(p[2 * s + 1][0], p[2 * s + 1][1]), cvtpk(p[2 * s + 1][2], p[2 * s + 1][3])};
            pb[s] = __builtin_bit_cast(bf16x8, bi);
        }

        // ---- PV: accO (O^T tile) += V^T x P^T ----
        __builtin_amdgcn_s_setprio(1);
        #pragma unroll
        for (int mt = 0; mt < 2; ++mt)
            #pragma unroll
            for (int s = 0; s < 4; ++s) {
                bf16x8 av = *(const bf16x8*)&VsT[cur][(mt * 16 + r15) * 136 + 32 * s + 8 * g];
                accO[mt] = __builtin_amdgcn_mfma_f32_16x16x32_bf16(av, pb[s], accO[mt], 0, 0, 0);
            }
        __builtin_amdgcn_s_setprio(0);

        // ---- write-late: V(kt+1) regs -> LDS, mask bias ----
        if (kt < 3) {
            #pragma unroll
            for (int qq = 0; qq < 2; ++qq) {
                int key = l + 64 * qq;
                #pragma unroll
                for (int i = 0; i < 4; ++i) {
                    unsigned u = (unsigned)vr[qq][i];
                    VsT[nxt][(wid * 8 + 2 * i) * 136 + key] = (unsigned short)(u & 0xffff);
                    VsT[nxt][(wid * 8 + 2 * i + 1) * 136 + key] = (unsigned short)(u >> 16);
                }
            }
            if (tid < 128) Mb[nxt][tid] = (mraw != 0) ? -1e9f : 0.f;
        }
        __syncthreads();
    }

    const float inv = 1.f / lrun;
    const size_t orow = (size_t)bn * 512 + qt * 64 + wid * 16 + r15;
    #pragma unroll
    for (int mt = 0; mt < 2; ++mt) {
        ushort4 o;
        o.x = f2bf(accO[mt][0] * inv);
        o.y = f2bf(accO[mt][1] * inv);
        o.z = f2bf(accO[mt][2] * inv);
        o.w = f2bf(accO[mt][3] * inv);
        *(ushort4*)&ctx[orow * 256 + h * 32 + mt * 16 + 4 * g] = o;
    }
}

extern "C" void kernel_launch(void* const* d_in, const int* in_sizes, int n_in,
                              void* d_out, int out_size, void* d_ws, size_t ws_size,
                              hipStream_t stream) {
    const float* query = (const float*)d_in[0];
    const float* key   = (const float*)d_in[1];
    const float* value = (const float*)d_in[2];
    const int*   kpm   = (const int*)d_in[3];
    const float* w_pos = (const float*)d_in[4];
    const float* b_pos = (const float*)d_in[5];
    const float* w_vel = (const float*)d_in[6];
    const float* w_acc = (const float*)d_in[7];
    const float* Wq    = (const float*)d_in[8];
    const float* bq    = (const float*)d_in[9];
    const float* Wk    = (const float*)d_in[10];
    const float* bk    = (const float*)d_in[11];
    const float* Wv    = (const float*)d_in[12];
    const float* bv    = (const float*)d_in[13];
    const float* Wo    = (const float*)d_in[14];
    const float* bo    = (const float*)d_in[15];

    unsigned char* w = (unsigned char*)d_ws;
    unsigned short* XPQ = (unsigned short*)(w + OFF_XPQ);
    unsigned short* XPK = (unsigned short*)(w + OFF_XPK);
    unsigned short* VB  = (unsigned short*)(w + OFF_VB);
    unsigned short* BTQ = (unsigned short*)(w + OFF_BTQ);
    unsigned short* BTK = (unsigned short*)(w + OFF_BTK);
    float*          BEFF= (float*)(w + OFF_BEFF);
    unsigned short* WVT = (unsigned short*)(w + OFF_WVT);
    unsigned short* WOT = (unsigned short*)(w + OFF_WOT);
    unsigned short* QB  = (unsigned short*)(w + OFF_QB);
    unsigned short* KB  = (unsigned short*)(w + OFF_KB);
    unsigned short* VV  = (unsigned short*)(w + OFF_VV);
    unsigned short* CTX = (unsigned short*)(w + OFF_CTX);

    cvtprep<<<8210, 256, 0, stream>>>(query, key, value, XPQ, XPK, VB,
                                      Wq, Wk, bq, bk, w_pos, w_vel, w_acc, b_pos,
                                      Wv, Wo, BTQ, BTK, BEFF, WVT, WOT);

    proj_fused<<<dim3(256, 2, 3), 256, 0, stream>>>(XPQ, XPK, VB, BTQ, BTK, WVT,
                                                    BEFF, bv, QB, KB, VV);

    attn_mfma<<<dim3(8, 256), 256, 0, stream>>>(QB, KB, VV, kpm, CTX);

    outproj<<<dim3(256, 2), 256, 0, stream>>>(CTX, WOT, bo, (float*)d_out);
}

// Round 5
// 95.172 us; speedup vs baseline: 4.9893x; 1.0157x over previous
//
#include <hip/hip_runtime.h>
#include <math.h>

// B=4, N=8, T=512, D=256, H=8, DK=32. BN=32, ROWS=16384.
// R5: 32x32x16 MFMA GEMMs (64Mx256N, BK=64, dbuf), conversion fused into
// A-staging (no XPQ/XPK/VB pass), KVBLK=128 attention, 4 launches.

typedef __attribute__((ext_vector_type(8))) short bf16x8;
typedef __attribute__((ext_vector_type(4))) float f32x4;
typedef __attribute__((ext_vector_type(16))) float f32x16;
typedef __attribute__((ext_vector_type(4))) int i32x4;

__device__ __forceinline__ unsigned short f2bf(float f) {
    unsigned u = __float_as_uint(f);
    return (unsigned short)((u + 0x7fff + ((u >> 16) & 1)) >> 16);
}
__device__ __forceinline__ float bf2f(unsigned short h) {
    return __uint_as_float(((unsigned)h) << 16);
}
__device__ __forceinline__ float ex2(float x) {
    float r; asm("v_exp_f32 %0, %1" : "=v"(r) : "v"(x)); return r;
}
__device__ __forceinline__ int cvtpk(float lo, float hi) {
    int r; asm("v_cvt_pk_bf16_f32 %0, %1, %2" : "=v"(r) : "v"(lo), "v"(hi)); return r;
}
__device__ __forceinline__ void gll16(const void* gsrc, const void* ldst) {
    __builtin_amdgcn_global_load_lds(
        (const __attribute__((address_space(1))) unsigned int*)gsrc,
        (__attribute__((address_space(3))) unsigned int*)ldst, 16, 0, 0);
}

// scale(1/sqrt(32)) * log2(e): folded into Q projection -> softmax in exp2 domain
#define SCL (0.17677669529663689f * 1.4426950408889634f)

// ---- workspace byte offsets ----
#define OFF_BTQ  25231360u
#define OFF_BTK  25624576u
#define OFF_BEFF 26017792u
#define OFF_WVT  26019840u
#define OFF_WOT  26150912u
#define OFF_QB   26413056u
#define OFF_KB   34801664u
#define OFF_VV   43190272u
#define OFF_CTX  51578880u

// ---------------- weight prep (folded conv mats, transposes, biases) ----------------
__global__ __launch_bounds__(256) void prep(const float* __restrict__ Wq,
                                            const float* __restrict__ Wk,
                                            const float* __restrict__ bq,
                                            const float* __restrict__ bk,
                                            const float* __restrict__ wp,
                                            const float* __restrict__ wv,
                                            const float* __restrict__ wa,
                                            const float* __restrict__ b_pos,
                                            const float* __restrict__ Wv,
                                            const float* __restrict__ Wo,
                                            unsigned short* __restrict__ BtQ,
                                            unsigned short* __restrict__ BtK,
                                            float* __restrict__ beff,
                                            unsigned short* __restrict__ WVT,
                                            unsigned short* __restrict__ WOT) {
    int bid = blockIdx.x;
    if (bid < 1536) {
        int idx = bid * 256 + threadIdx.x;   // 2*3*256*256
        int which = idx / 196608;
        int r = idx - which * 196608;
        int j = r >> 16;
        int rem = r & 65535;
        int n = rem >> 8;
        int d = rem & 255;
        const float* W = which ? Wk : Wq;
        float val = wp[d * 3 + j] * W[d * 256 + n]
                  + wv[d * 3 + j] * W[(256 + d) * 256 + n]
                  + wa[d * 3 + j] * W[(512 + d) * 256 + n];
        if (!which) val *= SCL;
        (which ? BtK : BtQ)[n * 768 + j * 256 + d] = f2bf(val);
    } else if (bid < 2048) {
        int idx = (bid - 1536) * 256 + threadIdx.x;   // 2*65536
        int which = idx >> 16;
        int r = idx & 65535;
        int n = r >> 8, k = r & 255;
        if (!which) {
            WVT[n * 256 + k] = f2bf(Wv[k * 256 + n]);
        } else {
            float v = Wo[k * 256 + n];
            unsigned short hi = f2bf(v);
            WOT[n * 512 + k] = hi;
            WOT[n * 512 + 256 + k] = f2bf(v - bf2f(hi));
        }
    } else {
        int which = bid - 2048;
        int n = threadIdx.x;
        const float* W = which ? Wk : Wq;
        const float* bb = which ? bk : bq;
        float s = bb[n];
        for (int d = 0; d < 256; ++d) s = fmaf(b_pos[d], W[d * 256 + n], s);
        if (!which) s *= SCL;
        beff[which * 256 + n] = s;
    }
}

// ---------------- 32x32x16 MFMA GEMM body: 64M x 256N, BK=64, dbuf ----------------
// MODE 0: A bf16 [16384][256] via gll16 (col = k&255, for hi/lo split K).
// MODE 1: A fp32 im2col (padded seq, k = tap*256 + channel), reg-staged + cvt.
// MODE 2: A fp32 plain [16384][256], reg-staged + cvt.
// LDS rows = 64 shorts (8 chunks x 16B); physical chunk p holds logical p^(row&7).
template<int MODE, int KTOT, typename OutT>
__device__ __forceinline__ void gemm32_body(
    const void* Asrc, const unsigned short* __restrict__ Bt,
    const float* __restrict__ bias, OutT* __restrict__ Out,
    unsigned short* As, unsigned short* Bs)   // As: 2*4096, Bs: 2*16384 shorts
{
    const int tid = threadIdx.x;
    const int wid = tid >> 6, l = tid & 63;
    const int l31 = l & 31, h2 = l >> 5;
    const int m0 = blockIdx.x * 64;
    const int arow = tid >> 2, aq = tid & 3;   // A reg-stage coords

    f32x16 acc[2][2] = {};
    f32x4 ar[4];                               // in-flight A fp32 (MODE 1/2)

    auto issueB = [&](int k0, int b) {
        #pragma unroll
        for (int rr = 0; rr < 8; ++rr) {
            int row = rr * 32 + (tid >> 3);
            int srcc = ((tid & 7) ^ (row & 7)) * 8;
            gll16(Bt + (size_t)row * KTOT + k0 + srcc,
                  Bs + b * 16384 + (rr * 256 + wid * 64) * 8);
        }
    };
    auto issueA = [&](int k0, int b) {
        if constexpr (MODE == 0) {
            const unsigned short* A = (const unsigned short*)Asrc;
            #pragma unroll
            for (int rr = 0; rr < 2; ++rr) {
                int row = rr * 32 + (tid >> 3);
                int srcc = ((tid & 7) ^ (row & 7)) * 8;
                gll16(A + (size_t)(m0 + row) * 256 + (k0 & 255) + srcc,
                      As + b * 4096 + (rr * 256 + wid * 64) * 8);
            }
        } else {
            const float* X = (const float*)Asrc;
            bool valid = true;
            size_t off;
            if constexpr (MODE == 1) {
                int seq = m0 >> 9, t0 = m0 & 511;
                int st = t0 + arow + (k0 >> 8) - 1;
                valid = (st >= 0) && (st < 512);
                off = (size_t)(seq * 512 + st) * 256 + (k0 & 255) + aq * 16;
            } else {
                off = (size_t)(m0 + arow) * 256 + k0 + aq * 16;
            }
            #pragma unroll
            for (int i = 0; i < 4; ++i)
                ar[i] = valid ? *(const f32x4*)(X + off + i * 4) : (f32x4){0.f, 0.f, 0.f, 0.f};
        }
    };
    auto commitA = [&](int b) {
        if constexpr (MODE != 0) {
            i32x4 w0 = {cvtpk(ar[0][0], ar[0][1]), cvtpk(ar[0][2], ar[0][3]),
                        cvtpk(ar[1][0], ar[1][1]), cvtpk(ar[1][2], ar[1][3])};
            i32x4 w1 = {cvtpk(ar[2][0], ar[2][1]), cvtpk(ar[2][2], ar[2][3]),
                        cvtpk(ar[3][0], ar[3][1]), cvtpk(ar[3][2], ar[3][3])};
            int c0 = ((aq * 2) ^ (arow & 7)) * 8;
            int c1 = ((aq * 2 + 1) ^ (arow & 7)) * 8;
            *(i32x4*)&As[b * 4096 + arow * 64 + c0] = w0;
            *(i32x4*)&As[b * 4096 + arow * 64 + c1] = w1;
        }
    };

    issueA(0, 0);
    issueB(0, 0);
    commitA(0);
    __syncthreads();

    int b = 0;
    for (int k0 = 0; k0 < KTOT; k0 += 64, b ^= 1) {
        const bool more = (k0 + 64) < KTOT;
        if (more) { issueA(k0 + 64, b ^ 1); issueB(k0 + 64, b ^ 1); }
        const unsigned short* as = As + b * 4096;
        const unsigned short* bs = Bs + b * 16384;
        #pragma unroll
        for (int ks = 0; ks < 4; ++ks) {
            bf16x8 af[2], bfr[2];
            #pragma unroll
            for (int mt = 0; mt < 2; ++mt) {
                int r = mt * 32 + l31;
                af[mt] = *(const bf16x8*)&as[r * 64 + (((ks * 2 + h2) ^ (r & 7)) * 8)];
            }
            #pragma unroll
            for (int nt = 0; nt < 2; ++nt) {
                int r = wid * 64 + nt * 32 + l31;
                bfr[nt] = *(const bf16x8*)&bs[r * 64 + (((ks * 2 + h2) ^ (r & 7)) * 8)];
            }
            #pragma unroll
            for (int mt = 0; mt < 2; ++mt)
                #pragma unroll
                for (int nt = 0; nt < 2; ++nt)
                    acc[mt][nt] = __builtin_amdgcn_mfma_f32_32x32x16_bf16(af[mt], bfr[nt], acc[mt][nt], 0, 0, 0);
        }
        if (more) commitA(b ^ 1);
        __syncthreads();
    }

    // epilogue: C/D 32x32 layout: col = lane&31, row = (reg&3) + 8*(reg>>2) + 4*(lane>>5)
    #pragma unroll
    for (int nt = 0; nt < 2; ++nt) {
        const int col = wid * 64 + nt * 32 + l31;
        const float bb = bias[col];
        #pragma unroll
        for (int mt = 0; mt < 2; ++mt) {
            #pragma unroll
            for (int r = 0; r < 16; ++r) {
                const int row = m0 + mt * 32 + 4 * h2 + (r & 3) + 8 * (r >> 2);
                float v = acc[mt][nt][r] + bb;
                if constexpr (sizeof(OutT) == 2) Out[(size_t)row * 256 + col] = (OutT)f2bf(v);
                else Out[(size_t)row * 256 + col] = v;
            }
        }
    }
}

// one launch: z=0 Q-proj, z=1 K-proj (im2col fp32), z=2 V-proj (plain fp32)
__global__ __launch_bounds__(256) void proj_fused(
    const float* __restrict__ query, const float* __restrict__ key,
    const float* __restrict__ value,
    const unsigned short* __restrict__ BTQ, const unsigned short* __restrict__ BTK,
    const unsigned short* __restrict__ WVT,
    const float* __restrict__ BEFF, const float* __restrict__ bv,
    unsigned short* __restrict__ QB, unsigned short* __restrict__ KB,
    unsigned short* __restrict__ VV)
{
    __shared__ alignas(16) unsigned short As[2 * 4096];
    __shared__ alignas(16) unsigned short Bs[2 * 16384];
    const int z = blockIdx.z;
    if (z == 0)      gemm32_body<1, 768, unsigned short>(query, BTQ, BEFF, QB, As, Bs);
    else if (z == 1) gemm32_body<1, 768, unsigned short>(key, BTK, BEFF + 256, KB, As, Bs);
    else             gemm32_body<2, 256, unsigned short>(value, WVT, bv, VV, As, Bs);
}

__global__ __launch_bounds__(256) void outproj(
    const unsigned short* __restrict__ CTX, const unsigned short* __restrict__ WOT,
    const float* __restrict__ bo, float* __restrict__ Out)
{
    __shared__ alignas(16) unsigned short As[2 * 4096];
    __shared__ alignas(16) unsigned short Bs[2 * 16384];
    gemm32_body<0, 512, float>(CTX, WOT, bo, Out, As, Bs);
}

// ---------------- fused MFMA flash attention, KVBLK=128, dbuf ----------------
__global__ __launch_bounds__(256) void attn_mfma(const unsigned short* __restrict__ Qb,
                                                 const unsigned short* __restrict__ Kb,
                                                 const unsigned short* __restrict__ Vv,
                                                 const int* __restrict__ mask,
                                                 unsigned short* __restrict__ ctx) {
    __shared__ alignas(16) unsigned short Qs[64 * 32];
    __shared__ alignas(16) unsigned short Ks[2][128 * 32];   // chunk-xor (c ^ (row&3))
    __shared__ alignas(16) unsigned short VsT[2][32 * 136];  // [d][key], 17-chunk rows
    __shared__ float Mb[2][128];

    const int qt = blockIdx.x, bnh = blockIdx.y;
    const int bn = bnh >> 3, h = bnh & 7;
    const int tid = threadIdx.x, wid = tid >> 6, l = tid & 63;
    const int g = l >> 4, r15 = l & 15;
    const unsigned short* Qg = Qb + (size_t)bn * 512 * 256 + h * 32;
    const unsigned short* Kg = Kb + (size_t)bn * 512 * 256 + h * 32;
    const unsigned short* Vg = Vv + (size_t)bn * 512 * 256 + h * 32;
    const int* mp = mask + bn * 512;

    auto stageK = [&](int k0, int b) {
        #pragma unroll
        for (int qq = 0; qq < 2; ++qq) {
            int cidx = qq * 256 + wid * 64 + l;
            int row = cidx >> 2, csrc = ((cidx & 3) ^ (row & 3)) * 8;
            gll16(Kg + ((size_t)(k0 + row)) * 256 + csrc, &Ks[b][qq * 2048 + wid * 512]);
        }
    };

    // ---- prologue: Q, K0, V0, Mb0 ----
    {
        int cidx = wid * 64 + l;
        gll16(Qg + ((size_t)(qt * 64 + (cidx >> 2))) * 256 + (cidx & 3) * 8, Qs + wid * 512);
    }
    stageK(0, 0);
    {
        #pragma unroll
        for (int qq = 0; qq < 2; ++qq) {
            int key = l + 64 * qq;
            i32x4 vr = *(const i32x4*)(const void*)(Vg + (size_t)key * 256 + wid * 8);
            #pragma unroll
            for (int i = 0; i < 4; ++i) {
                unsigned u = (unsigned)vr[i];
                VsT[0][(wid * 8 + 2 * i) * 136 + key] = (unsigned short)(u & 0xffff);
                VsT[0][(wid * 8 + 2 * i + 1) * 136 + key] = (unsigned short)(u >> 16);
            }
        }
        if (tid < 128) Mb[0][tid] = (mp[tid] != 0) ? -1e9f : 0.f;
    }
    __syncthreads();

    const bf16x8 bq = *(const bf16x8*)&Qs[(wid * 16 + r15) * 32 + g * 8];

    float mrun = -1e30f, lrun = 0.f;
    f32x4 accO[2] = {};

    for (int kt = 0; kt < 4; ++kt) {
        const int cur = kt & 1, nxt = cur ^ 1;
        const int k0n = kt * 128 + 128;

        // ---- issue next-tile loads early ----
        i32x4 vr[2];
        int mraw = 0;
        if (kt < 3) {
            stageK(k0n, nxt);
            #pragma unroll
            for (int qq = 0; qq < 2; ++qq)
                vr[qq] = *(const i32x4*)(const void*)(Vg + ((size_t)(k0n + l + 64 * qq)) * 256 + wid * 8);
            if (tid < 128) mraw = mp[k0n + tid];
        }

        // ---- QK^T (swapped, permuted A rows), mask bias as MFMA C-in ----
        float p[8][4];
        float rmax = -3e38f;
        __builtin_amdgcn_s_setprio(1);
        #pragma unroll
        for (int t2 = 0; t2 < 8; ++t2) {
            const int base = 32 * (t2 >> 1) + 4 * (t2 & 1);
            const int arow = base + 8 * (r15 >> 2) + (r15 & 3);
            bf16x8 ak = *(const bf16x8*)&Ks[cur][arow * 32 + ((g ^ (arow & 3)) * 8)];
            f32x4 cin = *(const f32x4*)&Mb[cur][base + 8 * g];
            f32x4 st = __builtin_amdgcn_mfma_f32_16x16x32_bf16(ak, bq, cin, 0, 0, 0);
            #pragma unroll
            for (int r = 0; r < 4; ++r) p[t2][r] = st[r];
            rmax = fmaxf(rmax, fmaxf(fmaxf(st[0], st[1]), fmaxf(st[2], st[3])));
        }
        __builtin_amdgcn_s_setprio(0);
        rmax = fmaxf(rmax, __shfl_xor(rmax, 16, 64));
        rmax = fmaxf(rmax, __shfl_xor(rmax, 32, 64));

        if (__ballot(rmax > mrun)) {
            float mnew = fmaxf(mrun, rmax);
            float fs = ex2(mrun - mnew);
            lrun *= fs;
            accO[0] *= fs;
            accO[1] *= fs;
            mrun = mnew;
        }
        float psum = 0.f;
        #pragma unroll
        for (int t2 = 0; t2 < 8; ++t2)
            #pragma unroll
            for (int r = 0; r < 4; ++r) {
                float e = ex2(p[t2][r] - mrun);
                p[t2][r] = e;
                psum += e;
            }
        psum += __shfl_xor(psum, 16, 64);
        psum += __shfl_xor(psum, 32, 64);
        lrun += psum;

        // ---- pack P (lane holds exactly its PV B-frag keys) ----
        bf16x8 pb[4];
        #pragma unroll
        for (int s = 0; s < 4; ++s) {
            i32x4 bi = {cvtpk(p[2 * s][0], p[2 * s][1]), cvtpk(p[2 * s][2], p[2 * s][3]),
                        cvtpk(p[2 * s + 1][0], p[2 * s + 1][1]), cvtpk(p[2 * s + 1][2], p[2 * s + 1][3])};
            pb[s] = __builtin_bit_cast(bf16x8, bi);
        }

        // ---- PV: accO (O^T tile) += V^T x P^T ----
        __builtin_amdgcn_s_setprio(1);
        #pragma unroll
        for (int mt = 0; mt < 2; ++mt)
            #pragma unroll
            for (int s = 0; s < 4; ++s) {
                bf16x8 av = *(const bf16x8*)&VsT[cur][(mt * 16 + r15) * 136 + 32 * s + 8 * g];
                accO[mt] = __builtin_amdgcn_mfma_f32_16x16x32_bf16(av, pb[s], accO[mt], 0, 0, 0);
            }
        __builtin_amdgcn_s_setprio(0);

        // ---- write-late: V(kt+1) regs -> LDS, mask bias ----
        if (kt < 3) {
            #pragma unroll
            for (int qq = 0; qq < 2; ++qq) {
                int key = l + 64 * qq;
                #pragma unroll
                for (int i = 0; i < 4; ++i) {
                    unsigned u = (unsigned)vr[qq][i];
                    VsT[nxt][(wid * 8 + 2 * i) * 136 + key] = (unsigned short)(u & 0xffff);
                    VsT[nxt][(wid * 8 + 2 * i + 1) * 136 + key] = (unsigned short)(u >> 16);
                }
            }
            if (tid < 128) Mb[nxt][tid] = (mraw != 0) ? -1e9f : 0.f;
        }
        __syncthreads();
    }

    const float inv = 1.f / lrun;
    const size_t orow = (size_t)bn * 512 + qt * 64 + wid * 16 + r15;
    #pragma unroll
    for (int mt = 0; mt < 2; ++mt) {
        ushort4 o;
        o.x = f2bf(accO[mt][0] * inv);
        o.y = f2bf(accO[mt][1] * inv);
        o.z = f2bf(accO[mt][2] * inv);
        o.w = f2bf(accO[mt][3] * inv);
        *(ushort4*)&ctx[orow * 256 + h * 32 + mt * 16 + 4 * g] = o;
    }
}

extern "C" void kernel_launch(void* const* d_in, const int* in_sizes, int n_in,
                              void* d_out, int out_size, void* d_ws, size_t ws_size,
                              hipStream_t stream) {
    const float* query = (const float*)d_in[0];
    const float* key   = (const float*)d_in[1];
    const float* value = (const float*)d_in[2];
    const int*   kpm   = (const int*)d_in[3];
    const float* w_pos = (const float*)d_in[4];
    const float* b_pos = (const float*)d_in[5];
    const float* w_vel = (const float*)d_in[6];
    const float* w_acc = (const float*)d_in[7];
    const float* Wq    = (const float*)d_in[8];
    const float* bq    = (const float*)d_in[9];
    const float* Wk    = (const float*)d_in[10];
    const float* bk    = (const float*)d_in[11];
    const float* Wv    = (const float*)d_in[12];
    const float* bv    = (const float*)d_in[13];
    const float* Wo    = (const float*)d_in[14];
    const float* bo    = (const float*)d_in[15];

    unsigned char* w = (unsigned char*)d_ws;
    unsigned short* BTQ = (unsigned short*)(w + OFF_BTQ);
    unsigned short* BTK = (unsigned short*)(w + OFF_BTK);
    float*          BEFF= (float*)(w + OFF_BEFF);
    unsigned short* WVT = (unsigned short*)(w + OFF_WVT);
    unsigned short* WOT = (unsigned short*)(w + OFF_WOT);
    unsigned short* QB  = (unsigned short*)(w + OFF_QB);
    unsigned short* KB  = (unsigned short*)(w + OFF_KB);
    unsigned short* VV  = (unsigned short*)(w + OFF_VV);
    unsigned short* CTX = (unsigned short*)(w + OFF_CTX);

    prep<<<2050, 256, 0, stream>>>(Wq, Wk, bq, bk, w_pos, w_vel, w_acc, b_pos,
                                   Wv, Wo, BTQ, BTK, BEFF, WVT, WOT);

    proj_fused<<<dim3(256, 1, 3), 256, 0, stream>>>(query, key, value, BTQ, BTK, WVT,
                                                    BEFF, bv, QB, KB, VV);

    attn_mfma<<<dim3(8, 256), 256, 0, stream>>>(QB, KB, VV, kpm, CTX);

    outproj<<<256, 256, 0, stream>>>(CTX, WOT, bo, (float*)d_out);
}